// Round 9
// baseline (921.027 us; speedup 1.0000x reference)
//
#include <hip/hip_runtime.h>
#include <math.h>

typedef unsigned short u16;
typedef unsigned char u8;
typedef unsigned int u32;
typedef __attribute__((ext_vector_type(4))) float f32x4;
typedef __attribute__((ext_vector_type(4), aligned(4))) float f32x4u; // dword-aligned vector ld/st (rows stride 1025)
typedef __attribute__((ext_vector_type(8))) short s16x8;

#define DEV __device__ __forceinline__

constexpr int BB = 8, NN = 1025, CC = 1024, HH = 16;
constexpr int NP  = 1152;            // padded attn length: 9*128
constexpr int MP  = 8320;            // padded token count: 65*128
constexpr int TOK = BB * NN;         // 8200 real tokens
constexpr int MW  = 36;              // mask words per row (1152/32)
constexpr float NEGV = -65504.f;

DEV u16 f2bf(float f){ union { float f; unsigned u; } v; v.f = f; return (u16)((v.u + 0x7fffu + ((v.u >> 16) & 1u)) >> 16); }
DEV float bf2f(u16 u){ union { float f; unsigned u; } v; v.u = (unsigned)u << 16; return v.f; }
DEV u32 cvt_pk_bf16(float lo_, float hi_){
  u32 r; asm("v_cvt_pk_bf16_f32 %0, %1, %2" : "=v"(r) : "v"(lo_), "v"(hi_)); return r;
}

struct __align__(8) us4 { u16 x, y, z, w; };

typedef const __attribute__((address_space(1))) void gv_t;
typedef __attribute__((address_space(3))) void lv_t;
DEV void gload16(const void* g, void* l){
  __builtin_amdgcn_global_load_lds((gv_t*)g, (lv_t*)l, 16, 0, 0);
}

// ---------- weight convert + transpose: W[K][Nn] f32 -> Wt[Nn][K] bf16 ----------
__launch_bounds__(256)
__global__ void cvt_transpose(const float* __restrict__ W, u16* __restrict__ Wt, int K, int Nn){
  __shared__ float tile[32][33];
  const int n0 = blockIdx.x * 32, k0 = blockIdx.y * 32;
  const int tx = threadIdx.x & 31, ty = threadIdx.x >> 5;
#pragma unroll
  for (int i = 0; i < 4; i++)
    tile[ty + i * 8][tx] = W[(size_t)(k0 + ty + i * 8) * Nn + n0 + tx];
  __syncthreads();
#pragma unroll
  for (int i = 0; i < 4; i++){
    const int n = n0 + ty + i * 8;
    Wt[(size_t)n * K + k0 + tx] = f2bf(tile[tx][ty + i * 8]);
  }
}

// ---------- LayerNorm (fp32 in) -> bf16 out, rows >= validRows zeroed ----------
__launch_bounds__(256)
__global__ void ln_kernel(const float* __restrict__ x, const float* __restrict__ g,
                          const float* __restrict__ b, u16* __restrict__ out, int validRows){
  const int row = blockIdx.x, tid = threadIdx.x;
  const size_t base = (size_t)row * CC + tid * 4;
  if (row >= validRows){ us4 z{0,0,0,0}; *(us4*)(out + base) = z; return; }
  f32x4u v = *(const f32x4u*)(x + base);
  float s  = v[0] + v[1] + v[2] + v[3];
  float ss = v[0]*v[0] + v[1]*v[1] + v[2]*v[2] + v[3]*v[3];
#pragma unroll
  for (int o = 32; o; o >>= 1){ s += __shfl_xor(s, o, 64); ss += __shfl_xor(ss, o, 64); }
  __shared__ float ps[4], pq[4];
  if ((tid & 63) == 0){ ps[tid >> 6] = s; pq[tid >> 6] = ss; }
  __syncthreads();
  s  = ps[0] + ps[1] + ps[2] + ps[3];
  ss = pq[0] + pq[1] + pq[2] + pq[3];
  const float mu = s * (1.f / CC);
  const float rs = rsqrtf(ss * (1.f / CC) - mu * mu + 1e-5f);
  f32x4u gv = *(const f32x4u*)(g + tid * 4);
  f32x4u bv = *(const f32x4u*)(b + tid * 4);
  us4 o;
  o.x = f2bf((v[0]-mu)*rs*gv[0] + bv[0]);
  o.y = f2bf((v[1]-mu)*rs*gv[1] + bv[1]);
  o.z = f2bf((v[2]-mu)*rs*gv[2] + bv[2]);
  o.w = f2bf((v[3]-mu)*rs*gv[3] + bv[3]);
  *(us4*)(out + base) = o;
}

// ---------- generic NT bf16 GEMM ----------
template<int MODE>
__launch_bounds__(256)
__global__ void gemm_nt(const u16* __restrict__ A, const u16* __restrict__ Bt,
                        const float* __restrict__ bias, int K, int Nw,
                        const float* __restrict__ resid, float* __restrict__ fout,
                        u16* __restrict__ bout){
  __shared__ u16 As[128 * 32];
  __shared__ u16 Bs[128 * 32];
  const int tid = threadIdx.x;
  const int w = tid >> 6, l = tid & 63;
  const int wr = w >> 1, wc = w & 1;
  const int row0 = blockIdx.y * 128, col0 = blockIdx.x * 128;
  f32x4 acc[4][4] = {};
  for (int k0 = 0; k0 < K; k0 += 32){
    __syncthreads();
#pragma unroll
    for (int j = 0; j < 2; j++){
      const int ch = tid + j * 256;
      const int r = ch >> 2, co = (ch & 3) * 8;
      gload16(A  + (size_t)(row0 + r) * K + k0 + co, As + (size_t)ch * 8);
      gload16(Bt + (size_t)(col0 + r) * K + k0 + co, Bs + (size_t)ch * 8);
    }
    __syncthreads();
    s16x8 af[4], bf[4];
#pragma unroll
    for (int m = 0; m < 4; m++)
      af[m] = *(const s16x8*)(As + (wr * 64 + m * 16 + (l & 15)) * 32 + (l >> 4) * 8);
#pragma unroll
    for (int n = 0; n < 4; n++)
      bf[n] = *(const s16x8*)(Bs + (wc * 64 + n * 16 + (l & 15)) * 32 + (l >> 4) * 8);
#pragma unroll
    for (int m = 0; m < 4; m++)
#pragma unroll
      for (int n = 0; n < 4; n++)
        acc[m][n] = __builtin_amdgcn_mfma_f32_16x16x32_bf16(af[m], bf[n], acc[m][n], 0, 0, 0);
  }
#pragma unroll
  for (int m = 0; m < 4; m++){
#pragma unroll
    for (int n = 0; n < 4; n++){
      const int c = col0 + wc * 64 + n * 16 + (l & 15);
      const float bs = bias[c];
#pragma unroll
      for (int j = 0; j < 4; j++){
        const int r = row0 + wr * 64 + m * 16 + ((l >> 4) << 2) + j;
        float v = acc[m][n][j] + bs;
        if (MODE == 0){
          bout[(size_t)r * Nw + c] = f2bf(v);
        } else if (MODE == 1){
          const float xi = (r < TOK) ? resid[(size_t)r * CC + c] : 0.f;
          fout[(size_t)r * CC + c] = xi + v;
        } else if (MODE == 2){
          const float gx = 0.5f * v * (1.f + erff(v * 0.70710678118654752f));
          bout[(size_t)r * Nw + c] = f2bf(gx);
        } else {
          if (r < TOK) fout[(size_t)r * CC + c] = resid[(size_t)r * CC + c] + v;
        }
      }
    }
  }
}

// ---------- reorder qkv_buf[MP][3072] -> q,k [bh][NP][64] (q pre-scaled), vT [bh][64][NP] ----------
__launch_bounds__(256)
__global__ void reorder_qkv(const u16* __restrict__ qkv, u16* __restrict__ q,
                            u16* __restrict__ k, u16* __restrict__ vT){
  __shared__ u16 vt[64][65];
  const int bh = blockIdx.y, b = bh >> 4, h = bh & 15;
  const int n0 = blockIdx.x * 64;
  const int tid = threadIdx.x;
  const int d = tid & 63, nl = tid >> 6;
#pragma unroll
  for (int i = 0; i < 16; i++){
    const int nlocal = nl * 16 + i;
    const int n = n0 + nlocal;
    u16 qv = 0, kv = 0, vv = 0;
    if (n < NN){
      const size_t t = (size_t)b * NN + n;
      const u16* p = qkv + t * 3072 + h * 64 + d;
      qv = f2bf(bf2f(p[0]) * 0.125f);
      kv = p[1024];
      vv = p[2048];
    }
    q[(size_t)bh * NP * 64 + (size_t)n * 64 + d] = qv;
    k[(size_t)bh * NP * 64 + (size_t)n * 64 + d] = kv;
    vt[nlocal][d] = vv;
  }
  __syncthreads();
#pragma unroll
  for (int i = 0; i < 16; i++){
    const int dd = (tid >> 6) * 16 + i;
    const int nn2 = tid & 63;
    vT[(size_t)bh * 64 * NP + (size_t)dd * NP + n0 + nn2] = vt[nn2][dd];
  }
}

// ---------- pack mask bytes into bits: mbits[b][row<NP][MW] ----------
__launch_bounds__(256)
__global__ void mask_pack(const u8* __restrict__ mask, u32* __restrict__ mbits){
  const int idx = blockIdx.x * 256 + threadIdx.x;
  if (idx >= BB * NP * MW) return;
  const int word = idx % MW;
  const int row  = (idx / MW) % NP;
  const int b    = idx / (MW * NP);
  u32 bits = 0;
  if (row < NN){
    const u8* mrow = mask + (size_t)b * NN * NN + (size_t)row * NN;
    const int c0 = word * 32;
    const int lim = (NN - c0 < 32) ? (NN - c0) : 32;
    for (int j = 0; j < lim; j++) bits |= (u32)(mrow[c0 + j] != 0) << j;
  }
  mbits[idx] = bits;
}

// ---------- flash attention v7: R8 + in-wave shuffle-coalesced finalize ----------
// ONE change vs R8: for ct<8 the mask/bias/S-store runs in a coalesced lane
// layout reached via in-wave shuffles (no LDS growth, no extra barriers):
//   forward: lane l handles rows row0+(l>>3), row0+8+(l>>3), cols p*32+(l&7)*4
//   finalize: coalesced bias f32x4u load, one mask word per 32-col pair,
//             full-line coalesced S store
//   reverse: shuffle finalized values back into MFMA layout for softmax/PV.
// ct==8 tail keeps R8's in-lane path verbatim.
__launch_bounds__(256)
__global__ void attn_flash(const u16* __restrict__ q, const u16* __restrict__ k,
                           const u16* __restrict__ vT, const float* __restrict__ bias,
                           const u32* __restrict__ mbits,
                           float* __restrict__ S, u16* __restrict__ obuf){
  __shared__ u16 Ks[128 * 64];     // 16 KB: K-tile, chunk ^= row&7 (source-side)
  __shared__ u16 Vs[64 * 128];     // 16 KB: V-tile (vT layout), chunk ^= row&15

  const int f = blockIdx.x;
  const int xcd = f & 7, ii = f >> 3;
  const int hl = ii / 144, rem = ii % 144;
  const int rt = rem >> 3, b = rem & 7;
  const int h = xcd * 2 + hl;
  const int bh = b * 16 + h;
  const int tid = threadIdx.x, w = tid >> 6, l = tid & 63;
  const int lg = l >> 4, lo = l & 15;
  const int row0 = rt * 64 + w * 16;
  const u16* qb = q + (size_t)bh * NP * 64;
  const u16* kb = k + (size_t)bh * NP * 64;
  const u16* vb = vT + (size_t)bh * 64 * NP;
  const float* bias_h = bias + (size_t)h * NN * NN;
  const u32* mrow_b = mbits + (size_t)b * NP * MW;
  float* Sb = S + (size_t)bh * NN * NN;

  s16x8 qf[2];
#pragma unroll
  for (int kk = 0; kk < 2; kk++)
    qf[kk] = *(const s16x8*)(qb + (size_t)(row0 + lo) * 64 + kk * 32 + lg * 8);

  float m_run = -1e30f, l_run = 0.f;
  f32x4 acc_o[4] = {};

  // shuffle-finalize lane constants
  const int qrow8 = l >> 3;                       // 0..7 (coalesced row within half)
  const int c4 = (l & 7) * 4;                     // col offset within 32-col pair
  const int srcF = qrow8 + (((l & 7) >> 1) << 4); // forward src lane (A); B = +8
  const int bsel = (l & 7) & 1;                   // forward reg select
  const int lR = (lo & 7) * 8 + (lg << 1);        // reverse src lane base (+b)
  const int hiRow = lo >> 3;                      // reverse A/B select

  for (int ct = 0; ct < 9; ct++){
    const int cb = ct * 128;
    __syncthreads();                       // prev tile's LDS reads done
    // ---- stage K tile (R8 verbatim): 1024 chunks of 16B ----
#pragma unroll
    for (int i = 0; i < 4; i++){
      const int chunk = tid + i * 256;
      const int row = chunk >> 3, cs = chunk & 7;
      const int cg = cs ^ (row & 7);
      gload16(kb + (size_t)(cb + row) * 64 + cg * 8, Ks + (size_t)chunk * 8);
    }
    // ---- stage V tile (R8 verbatim): 1024 chunks of 16B ----
#pragma unroll
    for (int i = 0; i < 4; i++){
      const int chunk = tid + i * 256;
      const int row = chunk >> 4, cs = chunk & 15;
      const int cg = cs ^ (row & 15);
      gload16(vb + (size_t)row * NP + cb + cg * 8, Vs + (size_t)chunk * 8);
    }
    __syncthreads();                       // staged (drains vmcnt)

    f32x4 sa[8] = {};
    // S^T = K_perm x Q  (kf from LDS, R8 verbatim)
#pragma unroll
    for (int m2 = 0; m2 < 8; m2++){
      const int rl = (m2 >> 1) * 32 + (lo >> 2) * 8 + (m2 & 1) * 4 + (lo & 3);
      const s16x8 kf0 = *(const s16x8*)(Ks + rl * 64 + ((lg ^ (rl & 7)) << 3));
      const s16x8 kf1 = *(const s16x8*)(Ks + rl * 64 + (((4 + lg) ^ (rl & 7)) << 3));
      sa[m2] = __builtin_amdgcn_mfma_f32_16x16x32_bf16(kf0, qf[0], sa[m2], 0, 0, 0);
      sa[m2] = __builtin_amdgcn_mfma_f32_16x16x32_bf16(kf1, qf[1], sa[m2], 0, 0, 0);
    }

    if (ct < 8){
      // ---- in-wave shuffle-coalesced finalize (mask+bias+S-store) ----
#pragma unroll
      for (int p = 0; p < 4; p++){
        f32x4 vA, vB;
#pragma unroll
        for (int jj = 0; jj < 4; jj++){
          const float a0 = __shfl(sa[2*p][jj],     srcF,     64);
          const float a1 = __shfl(sa[2*p + 1][jj], srcF,     64);
          const float b0 = __shfl(sa[2*p][jj],     srcF + 8, 64);
          const float b1 = __shfl(sa[2*p + 1][jj], srcF + 8, 64);
          vA[jj] = bsel ? a1 : a0;
          vB[jj] = bsel ? b1 : b0;
        }
        const int raA = row0 + qrow8;
        const int raB = row0 + 8 + qrow8;
        const int colg = cb + p * 32 + c4;
        if (raA < NN){
          const f32x4u bv = *(const f32x4u*)(bias_h + (size_t)raA * NN + colg);
          const u32 wd = mrow_b[(size_t)raA * MW + ct * 4 + p];
#pragma unroll
          for (int jj = 0; jj < 4; jj++)
            vA[jj] = (((wd >> (c4 + jj)) & 1u) ? NEGV : vA[jj]) + bv[jj];
          *(f32x4u*)(Sb + (size_t)raA * NN + colg) = vA;
        } else { vA[0] = vA[1] = vA[2] = vA[3] = -1e30f; }
        if (raB < NN){
          const f32x4u bv = *(const f32x4u*)(bias_h + (size_t)raB * NN + colg);
          const u32 wd = mrow_b[(size_t)raB * MW + ct * 4 + p];
#pragma unroll
          for (int jj = 0; jj < 4; jj++)
            vB[jj] = (((wd >> (c4 + jj)) & 1u) ? NEGV : vB[jj]) + bv[jj];
          *(f32x4u*)(Sb + (size_t)raB * NN + colg) = vB;
        } else { vB[0] = vB[1] = vB[2] = vB[3] = -1e30f; }
        // reverse: back to MFMA layout
#pragma unroll
        for (int b2 = 0; b2 < 2; b2++){
          f32x4 outv;
#pragma unroll
          for (int jj = 0; jj < 4; jj++){
            const float fa = __shfl(vA[jj], lR + b2, 64);
            const float fb = __shfl(vB[jj], lR + b2, 64);
            outv[jj] = hiRow ? fb : fa;
          }
          sa[2*p + b2] = outv;
        }
      }
    } else {
      // ---- tail tile ct==8 (R8 verbatim in-lane path) ----
      const int qr = row0 + lo;
      if (qr < NN){
        const u32* mrp = mrow_b + (size_t)qr * MW + ct * 4;
        u32 mb[4];
#pragma unroll
        for (int i = 0; i < 4; i++) mb[i] = mrp[i];
        const float* brow = bias_h + (size_t)qr * NN;
        float* srow = Sb + (size_t)qr * NN;
#pragma unroll
        for (int m2 = 0; m2 < 8; m2++){
          const int kc0 = cb + (m2 >> 1) * 32 + lg * 8 + (m2 & 1) * 4;
          const u32 bits = mb[m2 >> 1] >> (lg * 8 + (m2 & 1) * 4);
          f32x4 a = sa[m2];
#pragma unroll
          for (int jj = 0; jj < 4; jj++){
            if (kc0 + jj < NN){
              float v = ((bits >> jj) & 1u) ? NEGV : a[jj];
              v += brow[kc0 + jj];
              srow[kc0 + jj] = v;
              a[jj] = v;
            } else a[jj] = -1e30f;
          }
          sa[m2] = a;
        }
      } else {
        const f32x4 z = {0.f, 0.f, 0.f, 0.f};
#pragma unroll
        for (int m2 = 0; m2 < 8; m2++) sa[m2] = z;
      }
    }

    // online softmax (R8 verbatim)
    float sc;
    {
      float mt = -1e30f;
#pragma unroll
      for (int m2 = 0; m2 < 8; m2++){
        f32x4 a = sa[m2];
        mt = fmaxf(mt, fmaxf(fmaxf(a[0], a[1]), fmaxf(a[2], a[3])));
      }
      mt = fmaxf(mt, __shfl_xor(mt, 16, 64));
      mt = fmaxf(mt, __shfl_xor(mt, 32, 64));
      const float mn = fmaxf(m_run, mt);
      sc = __expf(m_run - mn);
      float p = 0.f;
#pragma unroll
      for (int m2 = 0; m2 < 8; m2++){
        f32x4 a = sa[m2];
        const float e0 = __expf(a[0] - mn), e1 = __expf(a[1] - mn);
        const float e2 = __expf(a[2] - mn), e3 = __expf(a[3] - mn);
        p += (e0 + e1) + (e2 + e3);
        sa[m2][0] = __uint_as_float(cvt_pk_bf16(e0, e1));
        sa[m2][1] = __uint_as_float(cvt_pk_bf16(e2, e3));
      }
      p += __shfl_xor(p, 16, 64);
      p += __shfl_xor(p, 32, 64);
      l_run = l_run * sc + p;
      m_run = mn;
    }
    // rescale O (R8 verbatim)
#pragma unroll
    for (int jj = 0; jj < 4; jj++){
      const float s = __shfl(sc, (l & 48) + lg * 4 + jj, 64);
#pragma unroll
      for (int nd = 0; nd < 4; nd++) acc_o[nd][jj] *= s;
    }
    // PV (R8 verbatim, vf from LDS)
#pragma unroll
    for (int kc = 0; kc < 4; kc++){
      union { u32 d[4]; s16x8 v8; } af;
      af.d[0] = __float_as_uint(sa[2 * kc][0]);
      af.d[1] = __float_as_uint(sa[2 * kc][1]);
      af.d[2] = __float_as_uint(sa[2 * kc + 1][0]);
      af.d[3] = __float_as_uint(sa[2 * kc + 1][1]);
#pragma unroll
      for (int nd = 0; nd < 4; nd++){
        const int vrow = nd * 16 + lo;
        const s16x8 vf = *(const s16x8*)(Vs + vrow * 128 + (((kc * 4 + lg) ^ (vrow & 15)) << 3));
        acc_o[nd] = __builtin_amdgcn_mfma_f32_16x16x32_bf16(af.v8, vf, acc_o[nd], 0, 0, 0);
      }
    }
  }
  // epilogue: O * 1/l (R8 verbatim)
  {
    const float li = 1.f / l_run;
#pragma unroll
    for (int jj = 0; jj < 4; jj++){
      const float il = __shfl(li, (l & 48) + lg * 4 + jj, 64);
      const int qr = row0 + lg * 4 + jj;
      if (qr < NN){
        const size_t base = ((size_t)b * NN + qr) * CC + (size_t)h * 64;
#pragma unroll
        for (int nd = 0; nd < 4; nd++)
          obuf[base + nd * 16 + lo] = f2bf(acc_o[nd][jj] * il);
      }
    }
  }
}

// ---------- zero pad rows of obuf (tokens TOK..MP) ----------
__launch_bounds__(256)
__global__ void zero_pad_rows(u16* __restrict__ buf){
  const size_t i = (size_t)blockIdx.x * 256 + threadIdx.x;
  buf[(size_t)TOK * CC + i] = 0;
}

extern "C" void kernel_launch(void* const* d_in, const int* in_sizes, int n_in,
                              void* d_out, int out_size, void* d_ws, size_t ws_size,
                              hipStream_t stream){
  const float* x     = (const float*)d_in[0];
  const float* rpb   = (const float*)d_in[1];
  const u8*    mask  = (const u8*)d_in[2];
  const float* ln1g  = (const float*)d_in[3];
  const float* ln1b  = (const float*)d_in[4];
  const float* qkvw  = (const float*)d_in[5];
  const float* qkvb  = (const float*)d_in[6];
  const float* projw = (const float*)d_in[7];
  const float* projb = (const float*)d_in[8];
  const float* ln2g  = (const float*)d_in[9];
  const float* ln2b  = (const float*)d_in[10];
  const float* fc1w  = (const float*)d_in[11];
  const float* fc1b  = (const float*)d_in[12];
  const float* fc2w  = (const float*)d_in[13];
  const float* fc2b  = (const float*)d_in[14];

  float* out_x = (float*)d_out;
  float* out_S = out_x + (size_t)BB * NN * CC;

  char* wsb = (char*)d_ws;
  size_t off = 0;
  auto alloc = [&](size_t bytes) -> char* {
    char* p = wsb + off; off += (bytes + 255) & ~(size_t)255; return p;
  };
  u16* h1     = (u16*)alloc((size_t)MP * CC * 2);
  u16* qkvbuf = (u16*)alloc((size_t)MP * 3072 * 2);
  u16* h3     = h1;                                    // [MP][4096] aliases h1+qkvbuf
  u16* qkvwt  = (u16*)alloc((size_t)3072 * 1024 * 2);
  u16* projwt = (u16*)alloc((size_t)1024 * 1024 * 2);
  u16* fc1wt  = (u16*)alloc((size_t)4096 * 1024 * 2);
  u16* fc2wt  = (u16*)alloc((size_t)1024 * 4096 * 2);
  u16* qq     = (u16*)alloc((size_t)128 * NP * 64 * 2);
  u16* kk     = (u16*)alloc((size_t)128 * NP * 64 * 2);
  u16* vT     = (u16*)alloc((size_t)128 * 64 * NP * 2);
  u32* mbits  = (u32*)alloc((size_t)BB * NP * MW * 4);
  u16* obuf   = (u16*)alloc((size_t)MP * CC * 2);
  float* x1   = (float*)alloc((size_t)MP * CC * 4);
  u16* h2in   = (u16*)alloc((size_t)MP * CC * 2);

  cvt_transpose<<<dim3(3072/32, 1024/32), 256, 0, stream>>>(qkvw, qkvwt, 1024, 3072);
  cvt_transpose<<<dim3(1024/32, 1024/32), 256, 0, stream>>>(projw, projwt, 1024, 1024);
  cvt_transpose<<<dim3(4096/32, 1024/32), 256, 0, stream>>>(fc1w, fc1wt, 1024, 4096);
  cvt_transpose<<<dim3(1024/32, 4096/32), 256, 0, stream>>>(fc2w, fc2wt, 4096, 1024);
  ln_kernel<<<MP, 256, 0, stream>>>(x, ln1g, ln1b, h1, TOK);
  gemm_nt<0><<<dim3(3072/128, MP/128), 256, 0, stream>>>(h1, qkvwt, qkvb, 1024, 3072, nullptr, nullptr, qkvbuf);
  reorder_qkv<<<dim3(NP/64, 128), 256, 0, stream>>>(qkvbuf, qq, kk, vT);
  mask_pack<<<(BB * NP * MW + 255) / 256, 256, 0, stream>>>(mask, mbits);
  zero_pad_rows<<<(MP - TOK) * CC / 256, 256, 0, stream>>>(obuf);
  attn_flash<<<dim3(2304), 256, 0, stream>>>(qq, kk, vT, rpb, mbits, out_S, obuf);
  gemm_nt<1><<<dim3(1024/128, MP/128), 256, 0, stream>>>(obuf, projwt, projb, 1024, 1024, x, x1, nullptr);
  ln_kernel<<<MP, 256, 0, stream>>>(x1, ln2g, ln2b, h2in, TOK);
  gemm_nt<2><<<dim3(4096/128, MP/128), 256, 0, stream>>>(h2in, fc1wt, fc1b, 1024, 4096, nullptr, nullptr, h3);
  gemm_nt<3><<<dim3(1024/128, MP/128), 256, 0, stream>>>(h3, fc2wt, fc2b, 4096, 1024, x1, out_x, nullptr);
}

// Round 10
// 819.022 us; speedup vs baseline: 1.1245x; 1.1245x over previous
//
#include <hip/hip_runtime.h>
#include <math.h>

typedef unsigned short u16;
typedef unsigned char u8;
typedef unsigned int u32;
typedef __attribute__((ext_vector_type(4))) float f32x4;
typedef __attribute__((ext_vector_type(4), aligned(4))) float f32x4u; // dword-aligned vector ld/st (rows stride 1025)
typedef __attribute__((ext_vector_type(8))) short s16x8;

#define DEV __device__ __forceinline__

constexpr int BB = 8, NN = 1025, CC = 1024, HH = 16;
constexpr int NP  = 1152;            // padded attn length: 9*128
constexpr int MP  = 8320;            // padded token count: 65*128
constexpr int TOK = BB * NN;         // 8200 real tokens
constexpr int MW  = 36;              // mask words per row (1152/32)
constexpr float NEGV = -65504.f;

DEV u16 f2bf(float f){ union { float f; unsigned u; } v; v.f = f; return (u16)((v.u + 0x7fffu + ((v.u >> 16) & 1u)) >> 16); }
DEV float bf2f(u16 u){ union { float f; unsigned u; } v; v.u = (unsigned)u << 16; return v.f; }
DEV u32 cvt_pk_bf16(float lo_, float hi_){
  u32 r; asm("v_cvt_pk_bf16_f32 %0, %1, %2" : "=v"(r) : "v"(lo_), "v"(hi_)); return r;
}

struct __align__(8) us4 { u16 x, y, z, w; };

typedef const __attribute__((address_space(1))) void gv_t;
typedef __attribute__((address_space(3))) void lv_t;
DEV void gload16(const void* g, void* l){
  __builtin_amdgcn_global_load_lds((gv_t*)g, (lv_t*)l, 16, 0, 0);
}

// ---------- weight convert + transpose: W[K][Nn] f32 -> Wt[Nn][K] bf16 ----------
__launch_bounds__(256)
__global__ void cvt_transpose(const float* __restrict__ W, u16* __restrict__ Wt, int K, int Nn){
  __shared__ float tile[32][33];
  const int n0 = blockIdx.x * 32, k0 = blockIdx.y * 32;
  const int tx = threadIdx.x & 31, ty = threadIdx.x >> 5;
#pragma unroll
  for (int i = 0; i < 4; i++)
    tile[ty + i * 8][tx] = W[(size_t)(k0 + ty + i * 8) * Nn + n0 + tx];
  __syncthreads();
#pragma unroll
  for (int i = 0; i < 4; i++){
    const int n = n0 + ty + i * 8;
    Wt[(size_t)n * K + k0 + tx] = f2bf(tile[tx][ty + i * 8]);
  }
}

// ---------- LayerNorm (fp32 in) -> bf16 out, rows >= validRows zeroed ----------
__launch_bounds__(256)
__global__ void ln_kernel(const float* __restrict__ x, const float* __restrict__ g,
                          const float* __restrict__ b, u16* __restrict__ out, int validRows){
  const int row = blockIdx.x, tid = threadIdx.x;
  const size_t base = (size_t)row * CC + tid * 4;
  if (row >= validRows){ us4 z{0,0,0,0}; *(us4*)(out + base) = z; return; }
  f32x4u v = *(const f32x4u*)(x + base);
  float s  = v[0] + v[1] + v[2] + v[3];
  float ss = v[0]*v[0] + v[1]*v[1] + v[2]*v[2] + v[3]*v[3];
#pragma unroll
  for (int o = 32; o; o >>= 1){ s += __shfl_xor(s, o, 64); ss += __shfl_xor(ss, o, 64); }
  __shared__ float ps[4], pq[4];
  if ((tid & 63) == 0){ ps[tid >> 6] = s; pq[tid >> 6] = ss; }
  __syncthreads();
  s  = ps[0] + ps[1] + ps[2] + ps[3];
  ss = pq[0] + pq[1] + pq[2] + pq[3];
  const float mu = s * (1.f / CC);
  const float rs = rsqrtf(ss * (1.f / CC) - mu * mu + 1e-5f);
  f32x4u gv = *(const f32x4u*)(g + tid * 4);
  f32x4u bv = *(const f32x4u*)(b + tid * 4);
  us4 o;
  o.x = f2bf((v[0]-mu)*rs*gv[0] + bv[0]);
  o.y = f2bf((v[1]-mu)*rs*gv[1] + bv[1]);
  o.z = f2bf((v[2]-mu)*rs*gv[2] + bv[2]);
  o.w = f2bf((v[3]-mu)*rs*gv[3] + bv[3]);
  *(us4*)(out + base) = o;
}

// ---------- generic NT bf16 GEMM ----------
template<int MODE>
__launch_bounds__(256)
__global__ void gemm_nt(const u16* __restrict__ A, const u16* __restrict__ Bt,
                        const float* __restrict__ bias, int K, int Nw,
                        const float* __restrict__ resid, float* __restrict__ fout,
                        u16* __restrict__ bout){
  __shared__ u16 As[128 * 32];
  __shared__ u16 Bs[128 * 32];
  const int tid = threadIdx.x;
  const int w = tid >> 6, l = tid & 63;
  const int wr = w >> 1, wc = w & 1;
  const int row0 = blockIdx.y * 128, col0 = blockIdx.x * 128;
  f32x4 acc[4][4] = {};
  for (int k0 = 0; k0 < K; k0 += 32){
    __syncthreads();
#pragma unroll
    for (int j = 0; j < 2; j++){
      const int ch = tid + j * 256;
      const int r = ch >> 2, co = (ch & 3) * 8;
      gload16(A  + (size_t)(row0 + r) * K + k0 + co, As + (size_t)ch * 8);
      gload16(Bt + (size_t)(col0 + r) * K + k0 + co, Bs + (size_t)ch * 8);
    }
    __syncthreads();
    s16x8 af[4], bf[4];
#pragma unroll
    for (int m = 0; m < 4; m++)
      af[m] = *(const s16x8*)(As + (wr * 64 + m * 16 + (l & 15)) * 32 + (l >> 4) * 8);
#pragma unroll
    for (int n = 0; n < 4; n++)
      bf[n] = *(const s16x8*)(Bs + (wc * 64 + n * 16 + (l & 15)) * 32 + (l >> 4) * 8);
#pragma unroll
    for (int m = 0; m < 4; m++)
#pragma unroll
      for (int n = 0; n < 4; n++)
        acc[m][n] = __builtin_amdgcn_mfma_f32_16x16x32_bf16(af[m], bf[n], acc[m][n], 0, 0, 0);
  }
#pragma unroll
  for (int m = 0; m < 4; m++){
#pragma unroll
    for (int n = 0; n < 4; n++){
      const int c = col0 + wc * 64 + n * 16 + (l & 15);
      const float bs = bias[c];
#pragma unroll
      for (int j = 0; j < 4; j++){
        const int r = row0 + wr * 64 + m * 16 + ((l >> 4) << 2) + j;
        float v = acc[m][n][j] + bs;
        if (MODE == 0){
          bout[(size_t)r * Nw + c] = f2bf(v);
        } else if (MODE == 1){
          const float xi = (r < TOK) ? resid[(size_t)r * CC + c] : 0.f;
          fout[(size_t)r * CC + c] = xi + v;
        } else if (MODE == 2){
          const float gx = 0.5f * v * (1.f + erff(v * 0.70710678118654752f));
          bout[(size_t)r * Nw + c] = f2bf(gx);
        } else {
          if (r < TOK) fout[(size_t)r * CC + c] = resid[(size_t)r * CC + c] + v;
        }
      }
    }
  }
}

// ---------- reorder qkv_buf[MP][3072] -> q,k [bh][NP][64] (q pre-scaled), vT [bh][64][NP] ----------
__launch_bounds__(256)
__global__ void reorder_qkv(const u16* __restrict__ qkv, u16* __restrict__ q,
                            u16* __restrict__ k, u16* __restrict__ vT){
  __shared__ u16 vt[64][65];
  const int bh = blockIdx.y, b = bh >> 4, h = bh & 15;
  const int n0 = blockIdx.x * 64;
  const int tid = threadIdx.x;
  const int d = tid & 63, nl = tid >> 6;
#pragma unroll
  for (int i = 0; i < 16; i++){
    const int nlocal = nl * 16 + i;
    const int n = n0 + nlocal;
    u16 qv = 0, kv = 0, vv = 0;
    if (n < NN){
      const size_t t = (size_t)b * NN + n;
      const u16* p = qkv + t * 3072 + h * 64 + d;
      qv = f2bf(bf2f(p[0]) * 0.125f);
      kv = p[1024];
      vv = p[2048];
    }
    q[(size_t)bh * NP * 64 + (size_t)n * 64 + d] = qv;
    k[(size_t)bh * NP * 64 + (size_t)n * 64 + d] = kv;
    vt[nlocal][d] = vv;
  }
  __syncthreads();
#pragma unroll
  for (int i = 0; i < 16; i++){
    const int dd = (tid >> 6) * 16 + i;
    const int nn2 = tid & 63;
    vT[(size_t)bh * 64 * NP + (size_t)dd * NP + n0 + nn2] = vt[nn2][dd];
  }
}

// ---------- pack mask bytes into bits: mbits[b][row<NP][MW] ----------
__launch_bounds__(256)
__global__ void mask_pack(const u8* __restrict__ mask, u32* __restrict__ mbits){
  const int idx = blockIdx.x * 256 + threadIdx.x;
  if (idx >= BB * NP * MW) return;
  const int word = idx % MW;
  const int row  = (idx / MW) % NP;
  const int b    = idx / (MW * NP);
  u32 bits = 0;
  if (row < NN){
    const u8* mrow = mask + (size_t)b * NN * NN + (size_t)row * NN;
    const int c0 = word * 32;
    const int lim = (NN - c0 < 32) ? (NN - c0) : 32;
    for (int j = 0; j < lim; j++) bits |= (u32)(mrow[c0 + j] != 0) << j;
  }
  mbits[idx] = bits;
}

// ---------- flash attention v8: R8 body, 128 q-rows/block (8 waves x 16 rows) ----------
// ONE change vs R8: block covers 128 q-rows with 8 waves (512 threads), so each
// K/V tile is staged into LDS once per 128 rows instead of once per 64 ->
// halves staging traffic and barrier-drain events per q-row. Per-wave state,
// fragment math, finalize, softmax, PV, epilogue are verbatim R8.
// Grid 1152 = 8 xcd * (2 hl * 9 rt * 8 b), b fastest per XCD.
__launch_bounds__(512)
__global__ void attn_flash(const u16* __restrict__ q, const u16* __restrict__ k,
                           const u16* __restrict__ vT, const float* __restrict__ bias,
                           const u32* __restrict__ mbits,
                           float* __restrict__ S, u16* __restrict__ obuf){
  __shared__ u16 Ks[128 * 64];     // 16 KB: K-tile, chunk ^= row&7 (source-side)
  __shared__ u16 Vs[64 * 128];     // 16 KB: V-tile (vT layout), chunk ^= row&15

  const int f = blockIdx.x;
  const int xcd = f & 7, ii = f >> 3;
  const int hl = ii / 72, rem = ii % 72;
  const int rt = rem >> 3, b = rem & 7;
  const int h = xcd * 2 + hl;
  const int bh = b * 16 + h;
  const int tid = threadIdx.x, w = tid >> 6, l = tid & 63;
  const int lg = l >> 4, lo = l & 15;
  const int row0 = rt * 128 + w * 16;
  const u16* qb = q + (size_t)bh * NP * 64;
  const u16* kb = k + (size_t)bh * NP * 64;
  const u16* vb = vT + (size_t)bh * 64 * NP;
  const float* bias_h = bias + (size_t)h * NN * NN;
  const u32* mrow_b = mbits + (size_t)b * NP * MW;
  float* Sb = S + (size_t)bh * NN * NN;

  s16x8 qf[2];
#pragma unroll
  for (int kk = 0; kk < 2; kk++)
    qf[kk] = *(const s16x8*)(qb + (size_t)(row0 + lo) * 64 + kk * 32 + lg * 8);

  float m_run = -1e30f, l_run = 0.f;
  f32x4 acc_o[4] = {};

  for (int ct = 0; ct < 9; ct++){
    const int cb = ct * 128;
    __syncthreads();                       // prev tile's LDS reads done
    // ---- stage K tile: 1024 chunks of 16B over 512 threads ----
#pragma unroll
    for (int i = 0; i < 2; i++){
      const int chunk = tid + i * 512;
      const int row = chunk >> 3, cs = chunk & 7;
      const int cg = cs ^ (row & 7);
      gload16(kb + (size_t)(cb + row) * 64 + cg * 8, Ks + (size_t)chunk * 8);
    }
    // ---- stage V tile: 1024 chunks of 16B over 512 threads ----
#pragma unroll
    for (int i = 0; i < 2; i++){
      const int chunk = tid + i * 512;
      const int row = chunk >> 4, cs = chunk & 15;
      const int cg = cs ^ (row & 15);
      gload16(vb + (size_t)row * NP + cb + cg * 8, Vs + (size_t)chunk * 8);
    }
    __syncthreads();                       // staged (drains vmcnt)

    f32x4 sa[8] = {};
    // S^T = K_perm x Q  (kf from LDS, R8 verbatim)
#pragma unroll
    for (int m2 = 0; m2 < 8; m2++){
      const int rl = (m2 >> 1) * 32 + (lo >> 2) * 8 + (m2 & 1) * 4 + (lo & 3);
      const s16x8 kf0 = *(const s16x8*)(Ks + rl * 64 + ((lg ^ (rl & 7)) << 3));
      const s16x8 kf1 = *(const s16x8*)(Ks + rl * 64 + (((4 + lg) ^ (rl & 7)) << 3));
      sa[m2] = __builtin_amdgcn_mfma_f32_16x16x32_bf16(kf0, qf[0], sa[m2], 0, 0, 0);
      sa[m2] = __builtin_amdgcn_mfma_f32_16x16x32_bf16(kf1, qf[1], sa[m2], 0, 0, 0);
    }
    // mask -> NEGV, + bias, write S; invalid k-cols -> -1e30  (verbatim R8)
    {
      const int qr = row0 + lo;
      if (qr < NN){
        const u32* mrp = mrow_b + (size_t)qr * MW + ct * 4;
        u32 mb[4];
#pragma unroll
        for (int i = 0; i < 4; i++) mb[i] = mrp[i];
        const float* brow = bias_h + (size_t)qr * NN;
        float* srow = Sb + (size_t)qr * NN;
#pragma unroll
        for (int m2 = 0; m2 < 8; m2++){
          const int kc0 = cb + (m2 >> 1) * 32 + lg * 8 + (m2 & 1) * 4;
          const u32 bits = mb[m2 >> 1] >> (lg * 8 + (m2 & 1) * 4);
          f32x4 a = sa[m2];
          if (kc0 + 3 < NN){
            f32x4u bv = *(const f32x4u*)(brow + kc0);
#pragma unroll
            for (int jj = 0; jj < 4; jj++){
              float v = ((bits >> jj) & 1u) ? NEGV : a[jj];
              a[jj] = v + bv[jj];
            }
            *(f32x4u*)(srow + kc0) = a;
          } else {
#pragma unroll
            for (int jj = 0; jj < 4; jj++){
              if (kc0 + jj < NN){
                float v = ((bits >> jj) & 1u) ? NEGV : a[jj];
                v += brow[kc0 + jj];
                srow[kc0 + jj] = v;
                a[jj] = v;
              } else a[jj] = -1e30f;
            }
          }
          sa[m2] = a;
        }
      } else {
        const f32x4 z = {0.f, 0.f, 0.f, 0.f};
#pragma unroll
        for (int m2 = 0; m2 < 8; m2++) sa[m2] = z;
      }
    }
    // online softmax (verbatim R8)
    float sc;
    {
      float mt = -1e30f;
#pragma unroll
      for (int m2 = 0; m2 < 8; m2++){
        f32x4 a = sa[m2];
        mt = fmaxf(mt, fmaxf(fmaxf(a[0], a[1]), fmaxf(a[2], a[3])));
      }
      mt = fmaxf(mt, __shfl_xor(mt, 16, 64));
      mt = fmaxf(mt, __shfl_xor(mt, 32, 64));
      const float mn = fmaxf(m_run, mt);
      sc = __expf(m_run - mn);
      float p = 0.f;
#pragma unroll
      for (int m2 = 0; m2 < 8; m2++){
        f32x4 a = sa[m2];
        const float e0 = __expf(a[0] - mn), e1 = __expf(a[1] - mn);
        const float e2 = __expf(a[2] - mn), e3 = __expf(a[3] - mn);
        p += (e0 + e1) + (e2 + e3);
        sa[m2][0] = __uint_as_float(cvt_pk_bf16(e0, e1));
        sa[m2][1] = __uint_as_float(cvt_pk_bf16(e2, e3));
      }
      p += __shfl_xor(p, 16, 64);
      p += __shfl_xor(p, 32, 64);
      l_run = l_run * sc + p;
      m_run = mn;
    }
    // rescale O (verbatim R8)
#pragma unroll
    for (int jj = 0; jj < 4; jj++){
      const float s = __shfl(sc, (l & 48) + lg * 4 + jj, 64);
#pragma unroll
      for (int nd = 0; nd < 4; nd++) acc_o[nd][jj] *= s;
    }
    // PV (verbatim R8, vf from LDS)
#pragma unroll
    for (int kc = 0; kc < 4; kc++){
      union { u32 d[4]; s16x8 v8; } af;
      af.d[0] = __float_as_uint(sa[2 * kc][0]);
      af.d[1] = __float_as_uint(sa[2 * kc][1]);
      af.d[2] = __float_as_uint(sa[2 * kc + 1][0]);
      af.d[3] = __float_as_uint(sa[2 * kc + 1][1]);
#pragma unroll
      for (int nd = 0; nd < 4; nd++){
        const int vrow = nd * 16 + lo;
        const s16x8 vf = *(const s16x8*)(Vs + vrow * 128 + (((kc * 4 + lg) ^ (vrow & 15)) << 3));
        acc_o[nd] = __builtin_amdgcn_mfma_f32_16x16x32_bf16(af.v8, vf, acc_o[nd], 0, 0, 0);
      }
    }
  }
  // epilogue: O * 1/l (verbatim R8)
  {
    const float li = 1.f / l_run;
#pragma unroll
    for (int jj = 0; jj < 4; jj++){
      const float il = __shfl(li, (l & 48) + lg * 4 + jj, 64);
      const int qr = row0 + lg * 4 + jj;
      if (qr < NN){
        const size_t base = ((size_t)b * NN + qr) * CC + (size_t)h * 64;
#pragma unroll
        for (int nd = 0; nd < 4; nd++)
          obuf[base + nd * 16 + lo] = f2bf(acc_o[nd][jj] * il);
      }
    }
  }
}

// ---------- zero pad rows of obuf (tokens TOK..MP) ----------
__launch_bounds__(256)
__global__ void zero_pad_rows(u16* __restrict__ buf){
  const size_t i = (size_t)blockIdx.x * 256 + threadIdx.x;
  buf[(size_t)TOK * CC + i] = 0;
}

extern "C" void kernel_launch(void* const* d_in, const int* in_sizes, int n_in,
                              void* d_out, int out_size, void* d_ws, size_t ws_size,
                              hipStream_t stream){
  const float* x     = (const float*)d_in[0];
  const float* rpb   = (const float*)d_in[1];
  const u8*    mask  = (const u8*)d_in[2];
  const float* ln1g  = (const float*)d_in[3];
  const float* ln1b  = (const float*)d_in[4];
  const float* qkvw  = (const float*)d_in[5];
  const float* qkvb  = (const float*)d_in[6];
  const float* projw = (const float*)d_in[7];
  const float* projb = (const float*)d_in[8];
  const float* ln2g  = (const float*)d_in[9];
  const float* ln2b  = (const float*)d_in[10];
  const float* fc1w  = (const float*)d_in[11];
  const float* fc1b  = (const float*)d_in[12];
  const float* fc2w  = (const float*)d_in[13];
  const float* fc2b  = (const float*)d_in[14];

  float* out_x = (float*)d_out;
  float* out_S = out_x + (size_t)BB * NN * CC;

  char* wsb = (char*)d_ws;
  size_t off = 0;
  auto alloc = [&](size_t bytes) -> char* {
    char* p = wsb + off; off += (bytes + 255) & ~(size_t)255; return p;
  };
  u16* h1     = (u16*)alloc((size_t)MP * CC * 2);
  u16* qkvbuf = (u16*)alloc((size_t)MP * 3072 * 2);
  u16* h3     = h1;                                    // [MP][4096] aliases h1+qkvbuf
  u16* qkvwt  = (u16*)alloc((size_t)3072 * 1024 * 2);
  u16* projwt = (u16*)alloc((size_t)1024 * 1024 * 2);
  u16* fc1wt  = (u16*)alloc((size_t)4096 * 1024 * 2);
  u16* fc2wt  = (u16*)alloc((size_t)1024 * 4096 * 2);
  u16* qq     = (u16*)alloc((size_t)128 * NP * 64 * 2);
  u16* kk     = (u16*)alloc((size_t)128 * NP * 64 * 2);
  u16* vT     = (u16*)alloc((size_t)128 * 64 * NP * 2);
  u32* mbits  = (u32*)alloc((size_t)BB * NP * MW * 4);
  u16* obuf   = (u16*)alloc((size_t)MP * CC * 2);
  float* x1   = (float*)alloc((size_t)MP * CC * 4);
  u16* h2in   = (u16*)alloc((size_t)MP * CC * 2);

  cvt_transpose<<<dim3(3072/32, 1024/32), 256, 0, stream>>>(qkvw, qkvwt, 1024, 3072);
  cvt_transpose<<<dim3(1024/32, 1024/32), 256, 0, stream>>>(projw, projwt, 1024, 1024);
  cvt_transpose<<<dim3(4096/32, 1024/32), 256, 0, stream>>>(fc1w, fc1wt, 1024, 4096);
  cvt_transpose<<<dim3(1024/32, 4096/32), 256, 0, stream>>>(fc2w, fc2wt, 4096, 1024);
  ln_kernel<<<MP, 256, 0, stream>>>(x, ln1g, ln1b, h1, TOK);
  gemm_nt<0><<<dim3(3072/128, MP/128), 256, 0, stream>>>(h1, qkvwt, qkvb, 1024, 3072, nullptr, nullptr, qkvbuf);
  reorder_qkv<<<dim3(NP/64, 128), 256, 0, stream>>>(qkvbuf, qq, kk, vT);
  mask_pack<<<(BB * NP * MW + 255) / 256, 256, 0, stream>>>(mask, mbits);
  zero_pad_rows<<<(MP - TOK) * CC / 256, 256, 0, stream>>>(obuf);
  attn_flash<<<dim3(1152), 512, 0, stream>>>(qq, kk, vT, rpb, mbits, out_S, obuf);
  gemm_nt<1><<<dim3(1024/128, MP/128), 256, 0, stream>>>(obuf, projwt, projb, 1024, 1024, x, x1, nullptr);
  ln_kernel<<<MP, 256, 0, stream>>>(x1, ln2g, ln2b, h2in, TOK);
  gemm_nt<2><<<dim3(4096/128, MP/128), 256, 0, stream>>>(h2in, fc1wt, fc1b, 1024, 4096, nullptr, nullptr, h3);
  gemm_nt<3><<<dim3(1024/128, MP/128), 256, 0, stream>>>(h3, fc2wt, fc2b, 4096, 1024, x1, out_x, nullptr);
}

// Round 11
// 789.065 us; speedup vs baseline: 1.1672x; 1.0380x over previous
//
#include <hip/hip_runtime.h>
#include <math.h>

typedef unsigned short u16;
typedef unsigned char u8;
typedef unsigned int u32;
typedef __attribute__((ext_vector_type(4))) float f32x4;
typedef __attribute__((ext_vector_type(4), aligned(4))) float f32x4u; // dword-aligned vector ld/st (rows stride 1025)
typedef __attribute__((ext_vector_type(8))) short s16x8;

#define DEV __device__ __forceinline__

constexpr int BB = 8, NN = 1025, CC = 1024, HH = 16;
constexpr int NP  = 1152;            // padded attn length: 9*128
constexpr int MP  = 8320;            // padded token count: 65*128
constexpr int TOK = BB * NN;         // 8200 real tokens
constexpr int MW  = 36;              // mask words per row (1152/32)
constexpr float NEGV = -65504.f;

DEV u16 f2bf(float f){ union { float f; unsigned u; } v; v.f = f; return (u16)((v.u + 0x7fffu + ((v.u >> 16) & 1u)) >> 16); }
DEV float bf2f(u16 u){ union { float f; unsigned u; } v; v.u = (unsigned)u << 16; return v.f; }
DEV u32 cvt_pk_bf16(float lo_, float hi_){
  u32 r; asm("v_cvt_pk_bf16_f32 %0, %1, %2" : "=v"(r) : "v"(lo_), "v"(hi_)); return r;
}

struct __align__(8) us4 { u16 x, y, z, w; };

typedef const __attribute__((address_space(1))) void gv_t;
typedef __attribute__((address_space(3))) void lv_t;
DEV void gload16(const void* g, void* l){
  __builtin_amdgcn_global_load_lds((gv_t*)g, (lv_t*)l, 16, 0, 0);
}

// ---------- weight convert + transpose: W[K][Nn] f32 -> Wt[Nn][K] bf16 ----------
__launch_bounds__(256)
__global__ void cvt_transpose(const float* __restrict__ W, u16* __restrict__ Wt, int K, int Nn){
  __shared__ float tile[32][33];
  const int n0 = blockIdx.x * 32, k0 = blockIdx.y * 32;
  const int tx = threadIdx.x & 31, ty = threadIdx.x >> 5;
#pragma unroll
  for (int i = 0; i < 4; i++)
    tile[ty + i * 8][tx] = W[(size_t)(k0 + ty + i * 8) * Nn + n0 + tx];
  __syncthreads();
#pragma unroll
  for (int i = 0; i < 4; i++){
    const int n = n0 + ty + i * 8;
    Wt[(size_t)n * K + k0 + tx] = f2bf(tile[tx][ty + i * 8]);
  }
}

// ---------- LayerNorm (fp32 in) -> bf16 out, rows >= validRows zeroed ----------
__launch_bounds__(256)
__global__ void ln_kernel(const float* __restrict__ x, const float* __restrict__ g,
                          const float* __restrict__ b, u16* __restrict__ out, int validRows){
  const int row = blockIdx.x, tid = threadIdx.x;
  const size_t base = (size_t)row * CC + tid * 4;
  if (row >= validRows){ us4 z{0,0,0,0}; *(us4*)(out + base) = z; return; }
  f32x4u v = *(const f32x4u*)(x + base);
  float s  = v[0] + v[1] + v[2] + v[3];
  float ss = v[0]*v[0] + v[1]*v[1] + v[2]*v[2] + v[3]*v[3];
#pragma unroll
  for (int o = 32; o; o >>= 1){ s += __shfl_xor(s, o, 64); ss += __shfl_xor(ss, o, 64); }
  __shared__ float ps[4], pq[4];
  if ((tid & 63) == 0){ ps[tid >> 6] = s; pq[tid >> 6] = ss; }
  __syncthreads();
  s  = ps[0] + ps[1] + ps[2] + ps[3];
  ss = pq[0] + pq[1] + pq[2] + pq[3];
  const float mu = s * (1.f / CC);
  const float rs = rsqrtf(ss * (1.f / CC) - mu * mu + 1e-5f);
  f32x4u gv = *(const f32x4u*)(g + tid * 4);
  f32x4u bv = *(const f32x4u*)(b + tid * 4);
  us4 o;
  o.x = f2bf((v[0]-mu)*rs*gv[0] + bv[0]);
  o.y = f2bf((v[1]-mu)*rs*gv[1] + bv[1]);
  o.z = f2bf((v[2]-mu)*rs*gv[2] + bv[2]);
  o.w = f2bf((v[3]-mu)*rs*gv[3] + bv[3]);
  *(us4*)(out + base) = o;
}

// ---------- generic NT bf16 GEMM ----------
template<int MODE>
__launch_bounds__(256)
__global__ void gemm_nt(const u16* __restrict__ A, const u16* __restrict__ Bt,
                        const float* __restrict__ bias, int K, int Nw,
                        const float* __restrict__ resid, float* __restrict__ fout,
                        u16* __restrict__ bout){
  __shared__ u16 As[128 * 32];
  __shared__ u16 Bs[128 * 32];
  const int tid = threadIdx.x;
  const int w = tid >> 6, l = tid & 63;
  const int wr = w >> 1, wc = w & 1;
  const int row0 = blockIdx.y * 128, col0 = blockIdx.x * 128;
  f32x4 acc[4][4] = {};
  for (int k0 = 0; k0 < K; k0 += 32){
    __syncthreads();
#pragma unroll
    for (int j = 0; j < 2; j++){
      const int ch = tid + j * 256;
      const int r = ch >> 2, co = (ch & 3) * 8;
      gload16(A  + (size_t)(row0 + r) * K + k0 + co, As + (size_t)ch * 8);
      gload16(Bt + (size_t)(col0 + r) * K + k0 + co, Bs + (size_t)ch * 8);
    }
    __syncthreads();
    s16x8 af[4], bf[4];
#pragma unroll
    for (int m = 0; m < 4; m++)
      af[m] = *(const s16x8*)(As + (wr * 64 + m * 16 + (l & 15)) * 32 + (l >> 4) * 8);
#pragma unroll
    for (int n = 0; n < 4; n++)
      bf[n] = *(const s16x8*)(Bs + (wc * 64 + n * 16 + (l & 15)) * 32 + (l >> 4) * 8);
#pragma unroll
    for (int m = 0; m < 4; m++)
#pragma unroll
      for (int n = 0; n < 4; n++)
        acc[m][n] = __builtin_amdgcn_mfma_f32_16x16x32_bf16(af[m], bf[n], acc[m][n], 0, 0, 0);
  }
#pragma unroll
  for (int m = 0; m < 4; m++){
#pragma unroll
    for (int n = 0; n < 4; n++){
      const int c = col0 + wc * 64 + n * 16 + (l & 15);
      const float bs = bias[c];
#pragma unroll
      for (int j = 0; j < 4; j++){
        const int r = row0 + wr * 64 + m * 16 + ((l >> 4) << 2) + j;
        float v = acc[m][n][j] + bs;
        if (MODE == 0){
          bout[(size_t)r * Nw + c] = f2bf(v);
        } else if (MODE == 1){
          const float xi = (r < TOK) ? resid[(size_t)r * CC + c] : 0.f;
          fout[(size_t)r * CC + c] = xi + v;
        } else if (MODE == 2){
          const float gx = 0.5f * v * (1.f + erff(v * 0.70710678118654752f));
          bout[(size_t)r * Nw + c] = f2bf(gx);
        } else {
          if (r < TOK) fout[(size_t)r * CC + c] = resid[(size_t)r * CC + c] + v;
        }
      }
    }
  }
}

// ---------- reorder qkv_buf[MP][3072] -> q,k [bh][NP][64] (q pre-scaled), vT [bh][64][NP] ----------
__launch_bounds__(256)
__global__ void reorder_qkv(const u16* __restrict__ qkv, u16* __restrict__ q,
                            u16* __restrict__ k, u16* __restrict__ vT){
  __shared__ u16 vt[64][65];
  const int bh = blockIdx.y, b = bh >> 4, h = bh & 15;
  const int n0 = blockIdx.x * 64;
  const int tid = threadIdx.x;
  const int d = tid & 63, nl = tid >> 6;
#pragma unroll
  for (int i = 0; i < 16; i++){
    const int nlocal = nl * 16 + i;
    const int n = n0 + nlocal;
    u16 qv = 0, kv = 0, vv = 0;
    if (n < NN){
      const size_t t = (size_t)b * NN + n;
      const u16* p = qkv + t * 3072 + h * 64 + d;
      qv = f2bf(bf2f(p[0]) * 0.125f);
      kv = p[1024];
      vv = p[2048];
    }
    q[(size_t)bh * NP * 64 + (size_t)n * 64 + d] = qv;
    k[(size_t)bh * NP * 64 + (size_t)n * 64 + d] = kv;
    vt[nlocal][d] = vv;
  }
  __syncthreads();
#pragma unroll
  for (int i = 0; i < 16; i++){
    const int dd = (tid >> 6) * 16 + i;
    const int nn2 = tid & 63;
    vT[(size_t)bh * 64 * NP + (size_t)dd * NP + n0 + nn2] = vt[nn2][dd];
  }
}

// ---------- pack mask bytes into bits: mbits[b][row<NP][MW] ----------
__launch_bounds__(256)
__global__ void mask_pack(const u8* __restrict__ mask, u32* __restrict__ mbits){
  const int idx = blockIdx.x * 256 + threadIdx.x;
  if (idx >= BB * NP * MW) return;
  const int word = idx % MW;
  const int row  = (idx / MW) % NP;
  const int b    = idx / (MW * NP);
  u32 bits = 0;
  if (row < NN){
    const u8* mrow = mask + (size_t)b * NN * NN + (size_t)row * NN;
    const int c0 = word * 32;
    const int lim = (NN - c0 < 32) ? (NN - c0) : 32;
    for (int j = 0; j < lim; j++) bits |= (u32)(mrow[c0 + j] != 0) << j;
  }
  mbits[idx] = bits;
}

// ---------- flash attention v9: R10 body + 2-phase K/V prefetch + setprio ----------
// Changes vs R10 (attn only):
//  (1) Ks/Vs double-buffered (64KB). Tile ct+1's global_load_lds issued at
//      iteration top; `s_waitcnt vmcnt(4)` waits only the CURRENT tile's 4
//      loads/thread (next tile's stay in flight across the barrier). Raw
//      s_barrier (NOT __syncthreads -> no vmcnt(0) drain). End-of-iter
//      s_barrier protects buffer reuse. sched_barrier(0) fences hoisting
//      (rule 18). Tail iter drains vmcnt(0).
//  (2) s_setprio(1/0) around the QK and PV MFMA clusters (T5).
// Compute/finalize/softmax/PV math verbatim R10.
__launch_bounds__(512)
__global__ void attn_flash(const u16* __restrict__ q, const u16* __restrict__ k,
                           const u16* __restrict__ vT, const float* __restrict__ bias,
                           const u32* __restrict__ mbits,
                           float* __restrict__ S, u16* __restrict__ obuf){
  __shared__ u16 Ks[2][128 * 64];  // 2 x 16 KB, chunk ^= row&7 (source-side)
  __shared__ u16 Vs[2][64 * 128];  // 2 x 16 KB, chunk ^= row&15

  const int f = blockIdx.x;
  const int xcd = f & 7, ii = f >> 3;
  const int hl = ii / 72, rem = ii % 72;
  const int rt = rem >> 3, b = rem & 7;
  const int h = xcd * 2 + hl;
  const int bh = b * 16 + h;
  const int tid = threadIdx.x, w = tid >> 6, l = tid & 63;
  const int lg = l >> 4, lo = l & 15;
  const int row0 = rt * 128 + w * 16;
  const u16* qb = q + (size_t)bh * NP * 64;
  const u16* kb = k + (size_t)bh * NP * 64;
  const u16* vb = vT + (size_t)bh * 64 * NP;
  const float* bias_h = bias + (size_t)h * NN * NN;
  const u32* mrow_b = mbits + (size_t)b * NP * MW;
  float* Sb = S + (size_t)bh * NN * NN;

  s16x8 qf[2];
#pragma unroll
  for (int kk = 0; kk < 2; kk++)
    qf[kk] = *(const s16x8*)(qb + (size_t)(row0 + lo) * 64 + kk * 32 + lg * 8);

  float m_run = -1e30f, l_run = 0.f;
  f32x4 acc_o[4] = {};

  // stage one 128-col K/V tile into buffer `buf`: 4 gload16 per thread
  auto stage = [&](int buf, int ct){
    const int cb = ct * 128;
#pragma unroll
    for (int i = 0; i < 2; i++){
      const int chunk = tid + i * 512;
      const int row = chunk >> 3, cs = chunk & 7;
      const int cg = cs ^ (row & 7);
      gload16(kb + (size_t)(cb + row) * 64 + cg * 8, Ks[buf] + (size_t)chunk * 8);
    }
#pragma unroll
    for (int i = 0; i < 2; i++){
      const int chunk = tid + i * 512;
      const int row = chunk >> 4, cs = chunk & 15;
      const int cg = cs ^ (row & 15);
      gload16(vb + (size_t)row * NP + cb + cg * 8, Vs[buf] + (size_t)chunk * 8);
    }
  };

  stage(0, 0);                           // prologue: tile 0 in flight

  for (int ct = 0; ct < 9; ct++){
    const int cb = ct * 128;
    const int cur = ct & 1;
    if (ct < 8){
      stage(cur ^ 1, ct + 1);            // issue next tile (flies during compute)
      asm volatile("s_waitcnt vmcnt(4)" ::: "memory");  // cur tile landed; next in flight
    } else {
      asm volatile("s_waitcnt vmcnt(0)" ::: "memory");  // tail: drain all
    }
    __builtin_amdgcn_s_barrier();        // all waves' cur-tile data visible
    __builtin_amdgcn_sched_barrier(0);
    const u16* KsC = Ks[cur];
    const u16* VsC = Vs[cur];

    f32x4 sa[8] = {};
    // S^T = K_perm x Q  (kf from LDS, R10 verbatim addressing)
    __builtin_amdgcn_s_setprio(1);
#pragma unroll
    for (int m2 = 0; m2 < 8; m2++){
      const int rl = (m2 >> 1) * 32 + (lo >> 2) * 8 + (m2 & 1) * 4 + (lo & 3);
      const s16x8 kf0 = *(const s16x8*)(KsC + rl * 64 + ((lg ^ (rl & 7)) << 3));
      const s16x8 kf1 = *(const s16x8*)(KsC + rl * 64 + (((4 + lg) ^ (rl & 7)) << 3));
      sa[m2] = __builtin_amdgcn_mfma_f32_16x16x32_bf16(kf0, qf[0], sa[m2], 0, 0, 0);
      sa[m2] = __builtin_amdgcn_mfma_f32_16x16x32_bf16(kf1, qf[1], sa[m2], 0, 0, 0);
    }
    __builtin_amdgcn_s_setprio(0);
    // mask -> NEGV, + bias, write S; invalid k-cols -> -1e30  (verbatim R10)
    {
      const int qr = row0 + lo;
      if (qr < NN){
        const u32* mrp = mrow_b + (size_t)qr * MW + ct * 4;
        u32 mb[4];
#pragma unroll
        for (int i = 0; i < 4; i++) mb[i] = mrp[i];
        const float* brow = bias_h + (size_t)qr * NN;
        float* srow = Sb + (size_t)qr * NN;
#pragma unroll
        for (int m2 = 0; m2 < 8; m2++){
          const int kc0 = cb + (m2 >> 1) * 32 + lg * 8 + (m2 & 1) * 4;
          const u32 bits = mb[m2 >> 1] >> (lg * 8 + (m2 & 1) * 4);
          f32x4 a = sa[m2];
          if (kc0 + 3 < NN){
            f32x4u bv = *(const f32x4u*)(brow + kc0);
#pragma unroll
            for (int jj = 0; jj < 4; jj++){
              float v = ((bits >> jj) & 1u) ? NEGV : a[jj];
              a[jj] = v + bv[jj];
            }
            *(f32x4u*)(srow + kc0) = a;
          } else {
#pragma unroll
            for (int jj = 0; jj < 4; jj++){
              if (kc0 + jj < NN){
                float v = ((bits >> jj) & 1u) ? NEGV : a[jj];
                v += brow[kc0 + jj];
                srow[kc0 + jj] = v;
                a[jj] = v;
              } else a[jj] = -1e30f;
            }
          }
          sa[m2] = a;
        }
      } else {
        const f32x4 z = {0.f, 0.f, 0.f, 0.f};
#pragma unroll
        for (int m2 = 0; m2 < 8; m2++) sa[m2] = z;
      }
    }
    // online softmax (verbatim R10)
    float sc;
    {
      float mt = -1e30f;
#pragma unroll
      for (int m2 = 0; m2 < 8; m2++){
        f32x4 a = sa[m2];
        mt = fmaxf(mt, fmaxf(fmaxf(a[0], a[1]), fmaxf(a[2], a[3])));
      }
      mt = fmaxf(mt, __shfl_xor(mt, 16, 64));
      mt = fmaxf(mt, __shfl_xor(mt, 32, 64));
      const float mn = fmaxf(m_run, mt);
      sc = __expf(m_run - mn);
      float p = 0.f;
#pragma unroll
      for (int m2 = 0; m2 < 8; m2++){
        f32x4 a = sa[m2];
        const float e0 = __expf(a[0] - mn), e1 = __expf(a[1] - mn);
        const float e2 = __expf(a[2] - mn), e3 = __expf(a[3] - mn);
        p += (e0 + e1) + (e2 + e3);
        sa[m2][0] = __uint_as_float(cvt_pk_bf16(e0, e1));
        sa[m2][1] = __uint_as_float(cvt_pk_bf16(e2, e3));
      }
      p += __shfl_xor(p, 16, 64);
      p += __shfl_xor(p, 32, 64);
      l_run = l_run * sc + p;
      m_run = mn;
    }
    // rescale O (verbatim R10)
#pragma unroll
    for (int jj = 0; jj < 4; jj++){
      const float s = __shfl(sc, (l & 48) + lg * 4 + jj, 64);
#pragma unroll
      for (int nd = 0; nd < 4; nd++) acc_o[nd][jj] *= s;
    }
    // PV (verbatim R10, vf from LDS)
    __builtin_amdgcn_s_setprio(1);
#pragma unroll
    for (int kc = 0; kc < 4; kc++){
      union { u32 d[4]; s16x8 v8; } af;
      af.d[0] = __float_as_uint(sa[2 * kc][0]);
      af.d[1] = __float_as_uint(sa[2 * kc][1]);
      af.d[2] = __float_as_uint(sa[2 * kc + 1][0]);
      af.d[3] = __float_as_uint(sa[2 * kc + 1][1]);
#pragma unroll
      for (int nd = 0; nd < 4; nd++){
        const int vrow = nd * 16 + lo;
        const s16x8 vf = *(const s16x8*)(VsC + vrow * 128 + (((kc * 4 + lg) ^ (vrow & 15)) << 3));
        acc_o[nd] = __builtin_amdgcn_mfma_f32_16x16x32_bf16(af.v8, vf, acc_o[nd], 0, 0, 0);
      }
    }
    __builtin_amdgcn_s_setprio(0);
    __builtin_amdgcn_s_barrier();        // all waves done reading cur buffer
    __builtin_amdgcn_sched_barrier(0);
  }
  // epilogue: O * 1/l (verbatim R10)
  {
    const float li = 1.f / l_run;
#pragma unroll
    for (int jj = 0; jj < 4; jj++){
      const float il = __shfl(li, (l & 48) + lg * 4 + jj, 64);
      const int qr = row0 + lg * 4 + jj;
      if (qr < NN){
        const size_t base = ((size_t)b * NN + qr) * CC + (size_t)h * 64;
#pragma unroll
        for (int nd = 0; nd < 4; nd++)
          obuf[base + nd * 16 + lo] = f2bf(acc_o[nd][jj] * il);
      }
    }
  }
}

// ---------- zero pad rows of obuf (tokens TOK..MP) ----------
__launch_bounds__(256)
__global__ void zero_pad_rows(u16* __restrict__ buf){
  const size_t i = (size_t)blockIdx.x * 256 + threadIdx.x;
  buf[(size_t)TOK * CC + i] = 0;
}

extern "C" void kernel_launch(void* const* d_in, const int* in_sizes, int n_in,
                              void* d_out, int out_size, void* d_ws, size_t ws_size,
                              hipStream_t stream){
  const float* x     = (const float*)d_in[0];
  const float* rpb   = (const float*)d_in[1];
  const u8*    mask  = (const u8*)d_in[2];
  const float* ln1g  = (const float*)d_in[3];
  const float* ln1b  = (const float*)d_in[4];
  const float* qkvw  = (const float*)d_in[5];
  const float* qkvb  = (const float*)d_in[6];
  const float* projw = (const float*)d_in[7];
  const float* projb = (const float*)d_in[8];
  const float* ln2g  = (const float*)d_in[9];
  const float* ln2b  = (const float*)d_in[10];
  const float* fc1w  = (const float*)d_in[11];
  const float* fc1b  = (const float*)d_in[12];
  const float* fc2w  = (const float*)d_in[13];
  const float* fc2b  = (const float*)d_in[14];

  float* out_x = (float*)d_out;
  float* out_S = out_x + (size_t)BB * NN * CC;

  char* wsb = (char*)d_ws;
  size_t off = 0;
  auto alloc = [&](size_t bytes) -> char* {
    char* p = wsb + off; off += (bytes + 255) & ~(size_t)255; return p;
  };
  u16* h1     = (u16*)alloc((size_t)MP * CC * 2);
  u16* qkvbuf = (u16*)alloc((size_t)MP * 3072 * 2);
  u16* h3     = h1;                                    // [MP][4096] aliases h1+qkvbuf
  u16* qkvwt  = (u16*)alloc((size_t)3072 * 1024 * 2);
  u16* projwt = (u16*)alloc((size_t)1024 * 1024 * 2);
  u16* fc1wt  = (u16*)alloc((size_t)4096 * 1024 * 2);
  u16* fc2wt  = (u16*)alloc((size_t)1024 * 4096 * 2);
  u16* qq     = (u16*)alloc((size_t)128 * NP * 64 * 2);
  u16* kk     = (u16*)alloc((size_t)128 * NP * 64 * 2);
  u16* vT     = (u16*)alloc((size_t)128 * 64 * NP * 2);
  u32* mbits  = (u32*)alloc((size_t)BB * NP * MW * 4);
  u16* obuf   = (u16*)alloc((size_t)MP * CC * 2);
  float* x1   = (float*)alloc((size_t)MP * CC * 4);
  u16* h2in   = (u16*)alloc((size_t)MP * CC * 2);

  cvt_transpose<<<dim3(3072/32, 1024/32), 256, 0, stream>>>(qkvw, qkvwt, 1024, 3072);
  cvt_transpose<<<dim3(1024/32, 1024/32), 256, 0, stream>>>(projw, projwt, 1024, 1024);
  cvt_transpose<<<dim3(4096/32, 1024/32), 256, 0, stream>>>(fc1w, fc1wt, 1024, 4096);
  cvt_transpose<<<dim3(1024/32, 4096/32), 256, 0, stream>>>(fc2w, fc2wt, 4096, 1024);
  ln_kernel<<<MP, 256, 0, stream>>>(x, ln1g, ln1b, h1, TOK);
  gemm_nt<0><<<dim3(3072/128, MP/128), 256, 0, stream>>>(h1, qkvwt, qkvb, 1024, 3072, nullptr, nullptr, qkvbuf);
  reorder_qkv<<<dim3(NP/64, 128), 256, 0, stream>>>(qkvbuf, qq, kk, vT);
  mask_pack<<<(BB * NP * MW + 255) / 256, 256, 0, stream>>>(mask, mbits);
  zero_pad_rows<<<(MP - TOK) * CC / 256, 256, 0, stream>>>(obuf);
  attn_flash<<<dim3(1152), 512, 0, stream>>>(qq, kk, vT, rpb, mbits, out_S, obuf);
  gemm_nt<1><<<dim3(1024/128, MP/128), 256, 0, stream>>>(obuf, projwt, projb, 1024, 1024, x, x1, nullptr);
  ln_kernel<<<MP, 256, 0, stream>>>(x1, ln2g, ln2b, h2in, TOK);
  gemm_nt<2><<<dim3(4096/128, MP/128), 256, 0, stream>>>(h2in, fc1wt, fc1b, 1024, 4096, nullptr, nullptr, h3);
  gemm_nt<3><<<dim3(1024/128, MP/128), 256, 0, stream>>>(h3, fc2wt, fc2b, 4096, 1024, x1, out_x, nullptr);
}

// Round 12
// 765.096 us; speedup vs baseline: 1.2038x; 1.0313x over previous
//
#include <hip/hip_runtime.h>
#include <math.h>

typedef unsigned short u16;
typedef unsigned char u8;
typedef unsigned int u32;
typedef __attribute__((ext_vector_type(4))) float f32x4;
typedef __attribute__((ext_vector_type(4), aligned(4))) float f32x4u; // dword-aligned vector ld/st (rows stride 1025)
typedef __attribute__((ext_vector_type(8))) short s16x8;

#define DEV __device__ __forceinline__

constexpr int BB = 8, NN = 1025, CC = 1024, HH = 16;
constexpr int NP  = 1152;            // padded attn length: 9*128
constexpr int MP  = 8320;            // padded token count: 65*128
constexpr int TOK = BB * NN;         // 8200 real tokens
constexpr int MW  = 36;              // mask words per row (1152/32)
constexpr float NEGV = -65504.f;

DEV u16 f2bf(float f){ union { float f; unsigned u; } v; v.f = f; return (u16)((v.u + 0x7fffu + ((v.u >> 16) & 1u)) >> 16); }
DEV float bf2f(u16 u){ union { float f; unsigned u; } v; v.u = (unsigned)u << 16; return v.f; }
DEV u32 cvt_pk_bf16(float lo_, float hi_){
  u32 r; asm("v_cvt_pk_bf16_f32 %0, %1, %2" : "=v"(r) : "v"(lo_), "v"(hi_)); return r;
}

struct __align__(8) us4 { u16 x, y, z, w; };

typedef const __attribute__((address_space(1))) void gv_t;
typedef __attribute__((address_space(3))) void lv_t;
DEV void gload16(const void* g, void* l){
  __builtin_amdgcn_global_load_lds((gv_t*)g, (lv_t*)l, 16, 0, 0);
}

// ---------- weight convert + transpose: W[K][Nn] f32 -> Wt[Nn][K] bf16 ----------
__launch_bounds__(256)
__global__ void cvt_transpose(const float* __restrict__ W, u16* __restrict__ Wt, int K, int Nn){
  __shared__ float tile[32][33];
  const int n0 = blockIdx.x * 32, k0 = blockIdx.y * 32;
  const int tx = threadIdx.x & 31, ty = threadIdx.x >> 5;
#pragma unroll
  for (int i = 0; i < 4; i++)
    tile[ty + i * 8][tx] = W[(size_t)(k0 + ty + i * 8) * Nn + n0 + tx];
  __syncthreads();
#pragma unroll
  for (int i = 0; i < 4; i++){
    const int n = n0 + ty + i * 8;
    Wt[(size_t)n * K + k0 + tx] = f2bf(tile[tx][ty + i * 8]);
  }
}

// ---------- LayerNorm (fp32 in) -> bf16 out, rows >= validRows zeroed ----------
__launch_bounds__(256)
__global__ void ln_kernel(const float* __restrict__ x, const float* __restrict__ g,
                          const float* __restrict__ b, u16* __restrict__ out, int validRows){
  const int row = blockIdx.x, tid = threadIdx.x;
  const size_t base = (size_t)row * CC + tid * 4;
  if (row >= validRows){ us4 z{0,0,0,0}; *(us4*)(out + base) = z; return; }
  f32x4u v = *(const f32x4u*)(x + base);
  float s  = v[0] + v[1] + v[2] + v[3];
  float ss = v[0]*v[0] + v[1]*v[1] + v[2]*v[2] + v[3]*v[3];
#pragma unroll
  for (int o = 32; o; o >>= 1){ s += __shfl_xor(s, o, 64); ss += __shfl_xor(ss, o, 64); }
  __shared__ float ps[4], pq[4];
  if ((tid & 63) == 0){ ps[tid >> 6] = s; pq[tid >> 6] = ss; }
  __syncthreads();
  s  = ps[0] + ps[1] + ps[2] + ps[3];
  ss = pq[0] + pq[1] + pq[2] + pq[3];
  const float mu = s * (1.f / CC);
  const float rs = rsqrtf(ss * (1.f / CC) - mu * mu + 1e-5f);
  f32x4u gv = *(const f32x4u*)(g + tid * 4);
  f32x4u bv = *(const f32x4u*)(b + tid * 4);
  us4 o;
  o.x = f2bf((v[0]-mu)*rs*gv[0] + bv[0]);
  o.y = f2bf((v[1]-mu)*rs*gv[1] + bv[1]);
  o.z = f2bf((v[2]-mu)*rs*gv[2] + bv[2]);
  o.w = f2bf((v[3]-mu)*rs*gv[3] + bv[3]);
  *(us4*)(out + base) = o;
}

// ---------- generic NT bf16 GEMM, 2-phase double-buffered (R11 attn pattern) ----------
// Per K-step: issue next tile's 4 global_load_lds/thread, s_waitcnt vmcnt(4)
// (current tile landed, next stays in flight across the barrier), raw s_barrier
// (no vmcnt(0) drain), compute, end s_barrier protects buffer reuse.
template<int MODE>
__launch_bounds__(256)
__global__ void gemm_nt(const u16* __restrict__ A, const u16* __restrict__ Bt,
                        const float* __restrict__ bias, int K, int Nw,
                        const float* __restrict__ resid, float* __restrict__ fout,
                        u16* __restrict__ bout){
  __shared__ u16 As[2][128 * 32];
  __shared__ u16 Bs[2][128 * 32];
  const int tid = threadIdx.x;
  const int w = tid >> 6, l = tid & 63;
  const int wr = w >> 1, wc = w & 1;
  const int row0 = blockIdx.y * 128, col0 = blockIdx.x * 128;

  auto stage = [&](int buf, int k0){
#pragma unroll
    for (int j = 0; j < 2; j++){
      const int ch = tid + j * 256;
      const int r = ch >> 2, co = (ch & 3) * 8;
      gload16(A  + (size_t)(row0 + r) * K + k0 + co, As[buf] + (size_t)ch * 8);
      gload16(Bt + (size_t)(col0 + r) * K + k0 + co, Bs[buf] + (size_t)ch * 8);
    }
  };

  f32x4 acc[4][4] = {};
  stage(0, 0);                                   // prologue: tile 0 in flight
  int it = 0;
  for (int k0 = 0; k0 < K; k0 += 32, ++it){
    const int cur = it & 1;
    if (k0 + 32 < K){
      stage(cur ^ 1, k0 + 32);                   // next tile flies during compute
      asm volatile("s_waitcnt vmcnt(4)" ::: "memory");
    } else {
      asm volatile("s_waitcnt vmcnt(0)" ::: "memory");
    }
    __builtin_amdgcn_s_barrier();                // cur tile visible to all waves
    __builtin_amdgcn_sched_barrier(0);
    const u16* AsC = As[cur];
    const u16* BsC = Bs[cur];
    s16x8 af[4], bf[4];
#pragma unroll
    for (int m = 0; m < 4; m++)
      af[m] = *(const s16x8*)(AsC + (wr * 64 + m * 16 + (l & 15)) * 32 + (l >> 4) * 8);
#pragma unroll
    for (int n = 0; n < 4; n++)
      bf[n] = *(const s16x8*)(BsC + (wc * 64 + n * 16 + (l & 15)) * 32 + (l >> 4) * 8);
#pragma unroll
    for (int m = 0; m < 4; m++)
#pragma unroll
      for (int n = 0; n < 4; n++)
        acc[m][n] = __builtin_amdgcn_mfma_f32_16x16x32_bf16(af[m], bf[n], acc[m][n], 0, 0, 0);
    __builtin_amdgcn_s_barrier();                // all waves done reading cur buffer
    __builtin_amdgcn_sched_barrier(0);
  }
#pragma unroll
  for (int m = 0; m < 4; m++){
#pragma unroll
    for (int n = 0; n < 4; n++){
      const int c = col0 + wc * 64 + n * 16 + (l & 15);
      const float bs = bias[c];
#pragma unroll
      for (int j = 0; j < 4; j++){
        const int r = row0 + wr * 64 + m * 16 + ((l >> 4) << 2) + j;
        float v = acc[m][n][j] + bs;
        if (MODE == 0){
          bout[(size_t)r * Nw + c] = f2bf(v);
        } else if (MODE == 1){
          const float xi = (r < TOK) ? resid[(size_t)r * CC + c] : 0.f;
          fout[(size_t)r * CC + c] = xi + v;
        } else if (MODE == 2){
          const float gx = 0.5f * v * (1.f + erff(v * 0.70710678118654752f));
          bout[(size_t)r * Nw + c] = f2bf(gx);
        } else {
          if (r < TOK) fout[(size_t)r * CC + c] = resid[(size_t)r * CC + c] + v;
        }
      }
    }
  }
}

// ---------- reorder qkv_buf[MP][3072] -> q,k [bh][NP][64] (q pre-scaled), vT [bh][64][NP] ----------
__launch_bounds__(256)
__global__ void reorder_qkv(const u16* __restrict__ qkv, u16* __restrict__ q,
                            u16* __restrict__ k, u16* __restrict__ vT){
  __shared__ u16 vt[64][65];
  const int bh = blockIdx.y, b = bh >> 4, h = bh & 15;
  const int n0 = blockIdx.x * 64;
  const int tid = threadIdx.x;
  const int d = tid & 63, nl = tid >> 6;
#pragma unroll
  for (int i = 0; i < 16; i++){
    const int nlocal = nl * 16 + i;
    const int n = n0 + nlocal;
    u16 qv = 0, kv = 0, vv = 0;
    if (n < NN){
      const size_t t = (size_t)b * NN + n;
      const u16* p = qkv + t * 3072 + h * 64 + d;
      qv = f2bf(bf2f(p[0]) * 0.125f);
      kv = p[1024];
      vv = p[2048];
    }
    q[(size_t)bh * NP * 64 + (size_t)n * 64 + d] = qv;
    k[(size_t)bh * NP * 64 + (size_t)n * 64 + d] = kv;
    vt[nlocal][d] = vv;
  }
  __syncthreads();
#pragma unroll
  for (int i = 0; i < 16; i++){
    const int dd = (tid >> 6) * 16 + i;
    const int nn2 = tid & 63;
    vT[(size_t)bh * 64 * NP + (size_t)dd * NP + n0 + nn2] = vt[nn2][dd];
  }
}

// ---------- pack mask bytes into bits: mbits[b][row<NP][MW] ----------
__launch_bounds__(256)
__global__ void mask_pack(const u8* __restrict__ mask, u32* __restrict__ mbits){
  const int idx = blockIdx.x * 256 + threadIdx.x;
  if (idx >= BB * NP * MW) return;
  const int word = idx % MW;
  const int row  = (idx / MW) % NP;
  const int b    = idx / (MW * NP);
  u32 bits = 0;
  if (row < NN){
    const u8* mrow = mask + (size_t)b * NN * NN + (size_t)row * NN;
    const int c0 = word * 32;
    const int lim = (NN - c0 < 32) ? (NN - c0) : 32;
    for (int j = 0; j < lim; j++) bits |= (u32)(mrow[c0 + j] != 0) << j;
  }
  mbits[idx] = bits;
}

// ---------- flash attention v9 (verbatim R11): 2-phase K/V prefetch + setprio ----------
__launch_bounds__(512)
__global__ void attn_flash(const u16* __restrict__ q, const u16* __restrict__ k,
                           const u16* __restrict__ vT, const float* __restrict__ bias,
                           const u32* __restrict__ mbits,
                           float* __restrict__ S, u16* __restrict__ obuf){
  __shared__ u16 Ks[2][128 * 64];  // 2 x 16 KB, chunk ^= row&7 (source-side)
  __shared__ u16 Vs[2][64 * 128];  // 2 x 16 KB, chunk ^= row&15

  const int f = blockIdx.x;
  const int xcd = f & 7, ii = f >> 3;
  const int hl = ii / 72, rem = ii % 72;
  const int rt = rem >> 3, b = rem & 7;
  const int h = xcd * 2 + hl;
  const int bh = b * 16 + h;
  const int tid = threadIdx.x, w = tid >> 6, l = tid & 63;
  const int lg = l >> 4, lo = l & 15;
  const int row0 = rt * 128 + w * 16;
  const u16* qb = q + (size_t)bh * NP * 64;
  const u16* kb = k + (size_t)bh * NP * 64;
  const u16* vb = vT + (size_t)bh * 64 * NP;
  const float* bias_h = bias + (size_t)h * NN * NN;
  const u32* mrow_b = mbits + (size_t)b * NP * MW;
  float* Sb = S + (size_t)bh * NN * NN;

  s16x8 qf[2];
#pragma unroll
  for (int kk = 0; kk < 2; kk++)
    qf[kk] = *(const s16x8*)(qb + (size_t)(row0 + lo) * 64 + kk * 32 + lg * 8);

  float m_run = -1e30f, l_run = 0.f;
  f32x4 acc_o[4] = {};

  auto stage = [&](int buf, int ct){
    const int cb = ct * 128;
#pragma unroll
    for (int i = 0; i < 2; i++){
      const int chunk = tid + i * 512;
      const int row = chunk >> 3, cs = chunk & 7;
      const int cg = cs ^ (row & 7);
      gload16(kb + (size_t)(cb + row) * 64 + cg * 8, Ks[buf] + (size_t)chunk * 8);
    }
#pragma unroll
    for (int i = 0; i < 2; i++){
      const int chunk = tid + i * 512;
      const int row = chunk >> 4, cs = chunk & 15;
      const int cg = cs ^ (row & 15);
      gload16(vb + (size_t)row * NP + cb + cg * 8, Vs[buf] + (size_t)chunk * 8);
    }
  };

  stage(0, 0);                           // prologue: tile 0 in flight

  for (int ct = 0; ct < 9; ct++){
    const int cb = ct * 128;
    const int cur = ct & 1;
    if (ct < 8){
      stage(cur ^ 1, ct + 1);            // issue next tile (flies during compute)
      asm volatile("s_waitcnt vmcnt(4)" ::: "memory");  // cur tile landed; next in flight
    } else {
      asm volatile("s_waitcnt vmcnt(0)" ::: "memory");  // tail: drain all
    }
    __builtin_amdgcn_s_barrier();        // all waves' cur-tile data visible
    __builtin_amdgcn_sched_barrier(0);
    const u16* KsC = Ks[cur];
    const u16* VsC = Vs[cur];

    f32x4 sa[8] = {};
    // S^T = K_perm x Q
    __builtin_amdgcn_s_setprio(1);
#pragma unroll
    for (int m2 = 0; m2 < 8; m2++){
      const int rl = (m2 >> 1) * 32 + (lo >> 2) * 8 + (m2 & 1) * 4 + (lo & 3);
      const s16x8 kf0 = *(const s16x8*)(KsC + rl * 64 + ((lg ^ (rl & 7)) << 3));
      const s16x8 kf1 = *(const s16x8*)(KsC + rl * 64 + (((4 + lg) ^ (rl & 7)) << 3));
      sa[m2] = __builtin_amdgcn_mfma_f32_16x16x32_bf16(kf0, qf[0], sa[m2], 0, 0, 0);
      sa[m2] = __builtin_amdgcn_mfma_f32_16x16x32_bf16(kf1, qf[1], sa[m2], 0, 0, 0);
    }
    __builtin_amdgcn_s_setprio(0);
    // mask -> NEGV, + bias, write S; invalid k-cols -> -1e30
    {
      const int qr = row0 + lo;
      if (qr < NN){
        const u32* mrp = mrow_b + (size_t)qr * MW + ct * 4;
        u32 mb[4];
#pragma unroll
        for (int i = 0; i < 4; i++) mb[i] = mrp[i];
        const float* brow = bias_h + (size_t)qr * NN;
        float* srow = Sb + (size_t)qr * NN;
#pragma unroll
        for (int m2 = 0; m2 < 8; m2++){
          const int kc0 = cb + (m2 >> 1) * 32 + lg * 8 + (m2 & 1) * 4;
          const u32 bits = mb[m2 >> 1] >> (lg * 8 + (m2 & 1) * 4);
          f32x4 a = sa[m2];
          if (kc0 + 3 < NN){
            f32x4u bv = *(const f32x4u*)(brow + kc0);
#pragma unroll
            for (int jj = 0; jj < 4; jj++){
              float v = ((bits >> jj) & 1u) ? NEGV : a[jj];
              a[jj] = v + bv[jj];
            }
            *(f32x4u*)(srow + kc0) = a;
          } else {
#pragma unroll
            for (int jj = 0; jj < 4; jj++){
              if (kc0 + jj < NN){
                float v = ((bits >> jj) & 1u) ? NEGV : a[jj];
                v += brow[kc0 + jj];
                srow[kc0 + jj] = v;
                a[jj] = v;
              } else a[jj] = -1e30f;
            }
          }
          sa[m2] = a;
        }
      } else {
        const f32x4 z = {0.f, 0.f, 0.f, 0.f};
#pragma unroll
        for (int m2 = 0; m2 < 8; m2++) sa[m2] = z;
      }
    }
    // online softmax
    float sc;
    {
      float mt = -1e30f;
#pragma unroll
      for (int m2 = 0; m2 < 8; m2++){
        f32x4 a = sa[m2];
        mt = fmaxf(mt, fmaxf(fmaxf(a[0], a[1]), fmaxf(a[2], a[3])));
      }
      mt = fmaxf(mt, __shfl_xor(mt, 16, 64));
      mt = fmaxf(mt, __shfl_xor(mt, 32, 64));
      const float mn = fmaxf(m_run, mt);
      sc = __expf(m_run - mn);
      float p = 0.f;
#pragma unroll
      for (int m2 = 0; m2 < 8; m2++){
        f32x4 a = sa[m2];
        const float e0 = __expf(a[0] - mn), e1 = __expf(a[1] - mn);
        const float e2 = __expf(a[2] - mn), e3 = __expf(a[3] - mn);
        p += (e0 + e1) + (e2 + e3);
        sa[m2][0] = __uint_as_float(cvt_pk_bf16(e0, e1));
        sa[m2][1] = __uint_as_float(cvt_pk_bf16(e2, e3));
      }
      p += __shfl_xor(p, 16, 64);
      p += __shfl_xor(p, 32, 64);
      l_run = l_run * sc + p;
      m_run = mn;
    }
    // rescale O
#pragma unroll
    for (int jj = 0; jj < 4; jj++){
      const float s = __shfl(sc, (l & 48) + lg * 4 + jj, 64);
#pragma unroll
      for (int nd = 0; nd < 4; nd++) acc_o[nd][jj] *= s;
    }
    // PV
    __builtin_amdgcn_s_setprio(1);
#pragma unroll
    for (int kc = 0; kc < 4; kc++){
      union { u32 d[4]; s16x8 v8; } af;
      af.d[0] = __float_as_uint(sa[2 * kc][0]);
      af.d[1] = __float_as_uint(sa[2 * kc][1]);
      af.d[2] = __float_as_uint(sa[2 * kc + 1][0]);
      af.d[3] = __float_as_uint(sa[2 * kc + 1][1]);
#pragma unroll
      for (int nd = 0; nd < 4; nd++){
        const int vrow = nd * 16 + lo;
        const s16x8 vf = *(const s16x8*)(VsC + vrow * 128 + (((kc * 4 + lg) ^ (vrow & 15)) << 3));
        acc_o[nd] = __builtin_amdgcn_mfma_f32_16x16x32_bf16(af.v8, vf, acc_o[nd], 0, 0, 0);
      }
    }
    __builtin_amdgcn_s_setprio(0);
    __builtin_amdgcn_s_barrier();        // all waves done reading cur buffer
    __builtin_amdgcn_sched_barrier(0);
  }
  // epilogue: O * 1/l
  {
    const float li = 1.f / l_run;
#pragma unroll
    for (int jj = 0; jj < 4; jj++){
      const float il = __shfl(li, (l & 48) + lg * 4 + jj, 64);
      const int qr = row0 + lg * 4 + jj;
      if (qr < NN){
        const size_t base = ((size_t)b * NN + qr) * CC + (size_t)h * 64;
#pragma unroll
        for (int nd = 0; nd < 4; nd++)
          obuf[base + nd * 16 + lo] = f2bf(acc_o[nd][jj] * il);
      }
    }
  }
}

// ---------- zero pad rows of obuf (tokens TOK..MP) ----------
__launch_bounds__(256)
__global__ void zero_pad_rows(u16* __restrict__ buf){
  const size_t i = (size_t)blockIdx.x * 256 + threadIdx.x;
  buf[(size_t)TOK * CC + i] = 0;
}

extern "C" void kernel_launch(void* const* d_in, const int* in_sizes, int n_in,
                              void* d_out, int out_size, void* d_ws, size_t ws_size,
                              hipStream_t stream){
  const float* x     = (const float*)d_in[0];
  const float* rpb   = (const float*)d_in[1];
  const u8*    mask  = (const u8*)d_in[2];
  const float* ln1g  = (const float*)d_in[3];
  const float* ln1b  = (const float*)d_in[4];
  const float* qkvw  = (const float*)d_in[5];
  const float* qkvb  = (const float*)d_in[6];
  const float* projw = (const float*)d_in[7];
  const float* projb = (const float*)d_in[8];
  const float* ln2g  = (const float*)d_in[9];
  const float* ln2b  = (const float*)d_in[10];
  const float* fc1w  = (const float*)d_in[11];
  const float* fc1b  = (const float*)d_in[12];
  const float* fc2w  = (const float*)d_in[13];
  const float* fc2b  = (const float*)d_in[14];

  float* out_x = (float*)d_out;
  float* out_S = out_x + (size_t)BB * NN * CC;

  char* wsb = (char*)d_ws;
  size_t off = 0;
  auto alloc = [&](size_t bytes) -> char* {
    char* p = wsb + off; off += (bytes + 255) & ~(size_t)255; return p;
  };
  u16* h1     = (u16*)alloc((size_t)MP * CC * 2);
  u16* qkvbuf = (u16*)alloc((size_t)MP * 3072 * 2);
  u16* h3     = h1;                                    // [MP][4096] aliases h1+qkvbuf
  u16* qkvwt  = (u16*)alloc((size_t)3072 * 1024 * 2);
  u16* projwt = (u16*)alloc((size_t)1024 * 1024 * 2);
  u16* fc1wt  = (u16*)alloc((size_t)4096 * 1024 * 2);
  u16* fc2wt  = (u16*)alloc((size_t)1024 * 4096 * 2);
  u16* qq     = (u16*)alloc((size_t)128 * NP * 64 * 2);
  u16* kk     = (u16*)alloc((size_t)128 * NP * 64 * 2);
  u16* vT     = (u16*)alloc((size_t)128 * 64 * NP * 2);
  u32* mbits  = (u32*)alloc((size_t)BB * NP * MW * 4);
  u16* obuf   = (u16*)alloc((size_t)MP * CC * 2);
  float* x1   = (float*)alloc((size_t)MP * CC * 4);
  u16* h2in   = (u16*)alloc((size_t)MP * CC * 2);

  cvt_transpose<<<dim3(3072/32, 1024/32), 256, 0, stream>>>(qkvw, qkvwt, 1024, 3072);
  cvt_transpose<<<dim3(1024/32, 1024/32), 256, 0, stream>>>(projw, projwt, 1024, 1024);
  cvt_transpose<<<dim3(4096/32, 1024/32), 256, 0, stream>>>(fc1w, fc1wt, 1024, 4096);
  cvt_transpose<<<dim3(1024/32, 4096/32), 256, 0, stream>>>(fc2w, fc2wt, 4096, 1024);
  ln_kernel<<<MP, 256, 0, stream>>>(x, ln1g, ln1b, h1, TOK);
  gemm_nt<0><<<dim3(3072/128, MP/128), 256, 0, stream>>>(h1, qkvwt, qkvb, 1024, 3072, nullptr, nullptr, qkvbuf);
  reorder_qkv<<<dim3(NP/64, 128), 256, 0, stream>>>(qkvbuf, qq, kk, vT);
  mask_pack<<<(BB * NP * MW + 255) / 256, 256, 0, stream>>>(mask, mbits);
  zero_pad_rows<<<(MP - TOK) * CC / 256, 256, 0, stream>>>(obuf);
  attn_flash<<<dim3(1152), 512, 0, stream>>>(qq, kk, vT, rpb, mbits, out_S, obuf);
  gemm_nt<1><<<dim3(1024/128, MP/128), 256, 0, stream>>>(obuf, projwt, projb, 1024, 1024, x, x1, nullptr);
  ln_kernel<<<MP, 256, 0, stream>>>(x1, ln2g, ln2b, h2in, TOK);
  gemm_nt<2><<<dim3(4096/128, MP/128), 256, 0, stream>>>(h2in, fc1wt, fc1b, 1024, 4096, nullptr, nullptr, h3);
  gemm_nt<3><<<dim3(1024/128, MP/128), 256, 0, stream>>>(h3, fc2wt, fc2b, 4096, 1024, x1, out_x, nullptr);
}

// Round 13
// 755.183 us; speedup vs baseline: 1.2196x; 1.0131x over previous
//
#include <hip/hip_runtime.h>
#include <math.h>

typedef unsigned short u16;
typedef unsigned char u8;
typedef unsigned int u32;
typedef __attribute__((ext_vector_type(4))) float f32x4;
typedef __attribute__((ext_vector_type(4), aligned(4))) float f32x4u; // dword-aligned vector ld/st (rows stride 1025)
typedef __attribute__((ext_vector_type(8))) short s16x8;

#define DEV __device__ __forceinline__

constexpr int BB = 8, NN = 1025, CC = 1024, HH = 16;
constexpr int NP  = 1152;            // padded attn length: 9*128
constexpr int MP  = 8320;            // padded token count: 65*128
constexpr int TOK = BB * NN;         // 8200 real tokens
constexpr int MW  = 36;              // mask words per row (1152/32)
constexpr float NEGV = -65504.f;

DEV u16 f2bf(float f){ union { float f; unsigned u; } v; v.f = f; return (u16)((v.u + 0x7fffu + ((v.u >> 16) & 1u)) >> 16); }
DEV float bf2f(u16 u){ union { float f; unsigned u; } v; v.u = (unsigned)u << 16; return v.f; }
DEV u32 cvt_pk_bf16(float lo_, float hi_){
  u32 r; asm("v_cvt_pk_bf16_f32 %0, %1, %2" : "=v"(r) : "v"(lo_), "v"(hi_)); return r;
}

struct __align__(8) us4 { u16 x, y, z, w; };

typedef const __attribute__((address_space(1))) void gv_t;
typedef __attribute__((address_space(3))) void lv_t;
DEV void gload16(const void* g, void* l){
  __builtin_amdgcn_global_load_lds((gv_t*)g, (lv_t*)l, 16, 0, 0);
}

// ---------- weight convert + transpose: W[K][Nn] f32 -> Wt[Nn][K] bf16 ----------
__launch_bounds__(256)
__global__ void cvt_transpose(const float* __restrict__ W, u16* __restrict__ Wt, int K, int Nn){
  __shared__ float tile[32][33];
  const int n0 = blockIdx.x * 32, k0 = blockIdx.y * 32;
  const int tx = threadIdx.x & 31, ty = threadIdx.x >> 5;
#pragma unroll
  for (int i = 0; i < 4; i++)
    tile[ty + i * 8][tx] = W[(size_t)(k0 + ty + i * 8) * Nn + n0 + tx];
  __syncthreads();
#pragma unroll
  for (int i = 0; i < 4; i++){
    const int n = n0 + ty + i * 8;
    Wt[(size_t)n * K + k0 + tx] = f2bf(tile[tx][ty + i * 8]);
  }
}

// ---------- LayerNorm (fp32 in) -> bf16 out, rows >= validRows zeroed ----------
__launch_bounds__(256)
__global__ void ln_kernel(const float* __restrict__ x, const float* __restrict__ g,
                          const float* __restrict__ b, u16* __restrict__ out, int validRows){
  const int row = blockIdx.x, tid = threadIdx.x;
  const size_t base = (size_t)row * CC + tid * 4;
  if (row >= validRows){ us4 z{0,0,0,0}; *(us4*)(out + base) = z; return; }
  f32x4u v = *(const f32x4u*)(x + base);
  float s  = v[0] + v[1] + v[2] + v[3];
  float ss = v[0]*v[0] + v[1]*v[1] + v[2]*v[2] + v[3]*v[3];
#pragma unroll
  for (int o = 32; o; o >>= 1){ s += __shfl_xor(s, o, 64); ss += __shfl_xor(ss, o, 64); }
  __shared__ float ps[4], pq[4];
  if ((tid & 63) == 0){ ps[tid >> 6] = s; pq[tid >> 6] = ss; }
  __syncthreads();
  s  = ps[0] + ps[1] + ps[2] + ps[3];
  ss = pq[0] + pq[1] + pq[2] + pq[3];
  const float mu = s * (1.f / CC);
  const float rs = rsqrtf(ss * (1.f / CC) - mu * mu + 1e-5f);
  f32x4u gv = *(const f32x4u*)(g + tid * 4);
  f32x4u bv = *(const f32x4u*)(b + tid * 4);
  us4 o;
  o.x = f2bf((v[0]-mu)*rs*gv[0] + bv[0]);
  o.y = f2bf((v[1]-mu)*rs*gv[1] + bv[1]);
  o.z = f2bf((v[2]-mu)*rs*gv[2] + bv[2]);
  o.w = f2bf((v[3]-mu)*rs*gv[3] + bv[3]);
  *(us4*)(out + base) = o;
}

// ---------- generic NT bf16 GEMM, 2-phase double-buffered + chunk-swizzled LDS ----------
// R12 pipeline (counted vmcnt(4), raw barriers) + ONE new concept: As/Bs chunk
// XOR-swizzle (source-side cs^(r&3), linear LDS dest; read slot lg^(row&3)) to
// cut the ds_read_b128 fragment-read conflict from 8-way to 4-way.
template<int MODE>
__launch_bounds__(256)
__global__ void gemm_nt(const u16* __restrict__ A, const u16* __restrict__ Bt,
                        const float* __restrict__ bias, int K, int Nw,
                        const float* __restrict__ resid, float* __restrict__ fout,
                        u16* __restrict__ bout){
  __shared__ u16 As[2][128 * 32];
  __shared__ u16 Bs[2][128 * 32];
  const int tid = threadIdx.x;
  const int w = tid >> 6, l = tid & 63;
  const int wr = w >> 1, wc = w & 1;
  const int lo = l & 15, lg = l >> 4;
  const int row0 = blockIdx.y * 128, col0 = blockIdx.x * 128;

  auto stage = [&](int buf, int k0){
#pragma unroll
    for (int j = 0; j < 2; j++){
      const int ch = tid + j * 256;
      const int r = ch >> 2, cs = ch & 3;
      const int cg = cs ^ (r & 3);              // source chunk for slot cs
      gload16(A  + (size_t)(row0 + r) * K + k0 + cg * 8, As[buf] + (size_t)ch * 8);
      gload16(Bt + (size_t)(col0 + r) * K + k0 + cg * 8, Bs[buf] + (size_t)ch * 8);
    }
  };

  f32x4 acc[4][4] = {};
  stage(0, 0);                                   // prologue: tile 0 in flight
  int it = 0;
  for (int k0 = 0; k0 < K; k0 += 32, ++it){
    const int cur = it & 1;
    if (k0 + 32 < K){
      stage(cur ^ 1, k0 + 32);                   // next tile flies during compute
      asm volatile("s_waitcnt vmcnt(4)" ::: "memory");
    } else {
      asm volatile("s_waitcnt vmcnt(0)" ::: "memory");
    }
    __builtin_amdgcn_s_barrier();                // cur tile visible to all waves
    __builtin_amdgcn_sched_barrier(0);
    const u16* AsC = As[cur];
    const u16* BsC = Bs[cur];
    s16x8 af[4], bf[4];
#pragma unroll
    for (int m = 0; m < 4; m++){
      const int rr = wr * 64 + m * 16 + lo;
      af[m] = *(const s16x8*)(AsC + rr * 32 + ((lg ^ (rr & 3)) << 3));
    }
#pragma unroll
    for (int n = 0; n < 4; n++){
      const int rr = wc * 64 + n * 16 + lo;
      bf[n] = *(const s16x8*)(BsC + rr * 32 + ((lg ^ (rr & 3)) << 3));
    }
#pragma unroll
    for (int m = 0; m < 4; m++)
#pragma unroll
      for (int n = 0; n < 4; n++)
        acc[m][n] = __builtin_amdgcn_mfma_f32_16x16x32_bf16(af[m], bf[n], acc[m][n], 0, 0, 0);
    __builtin_amdgcn_s_barrier();                // all waves done reading cur buffer
    __builtin_amdgcn_sched_barrier(0);
  }
#pragma unroll
  for (int m = 0; m < 4; m++){
#pragma unroll
    for (int n = 0; n < 4; n++){
      const int c = col0 + wc * 64 + n * 16 + (l & 15);
      const float bs = bias[c];
#pragma unroll
      for (int j = 0; j < 4; j++){
        const int r = row0 + wr * 64 + m * 16 + ((l >> 4) << 2) + j;
        float v = acc[m][n][j] + bs;
        if (MODE == 0){
          bout[(size_t)r * Nw + c] = f2bf(v);
        } else if (MODE == 1){
          const float xi = (r < TOK) ? resid[(size_t)r * CC + c] : 0.f;
          fout[(size_t)r * CC + c] = xi + v;
        } else if (MODE == 2){
          const float gx = 0.5f * v * (1.f + erff(v * 0.70710678118654752f));
          bout[(size_t)r * Nw + c] = f2bf(gx);
        } else {
          if (r < TOK) fout[(size_t)r * CC + c] = resid[(size_t)r * CC + c] + v;
        }
      }
    }
  }
}

// ---------- reorder qkv_buf[MP][3072] -> q,k [bh][NP][64] (q pre-scaled), vT [bh][64][NP] ----------
__launch_bounds__(256)
__global__ void reorder_qkv(const u16* __restrict__ qkv, u16* __restrict__ q,
                            u16* __restrict__ k, u16* __restrict__ vT){
  __shared__ u16 vt[64][65];
  const int bh = blockIdx.y, b = bh >> 4, h = bh & 15;
  const int n0 = blockIdx.x * 64;
  const int tid = threadIdx.x;
  const int d = tid & 63, nl = tid >> 6;
#pragma unroll
  for (int i = 0; i < 16; i++){
    const int nlocal = nl * 16 + i;
    const int n = n0 + nlocal;
    u16 qv = 0, kv = 0, vv = 0;
    if (n < NN){
      const size_t t = (size_t)b * NN + n;
      const u16* p = qkv + t * 3072 + h * 64 + d;
      qv = f2bf(bf2f(p[0]) * 0.125f);
      kv = p[1024];
      vv = p[2048];
    }
    q[(size_t)bh * NP * 64 + (size_t)n * 64 + d] = qv;
    k[(size_t)bh * NP * 64 + (size_t)n * 64 + d] = kv;
    vt[nlocal][d] = vv;
  }
  __syncthreads();
#pragma unroll
  for (int i = 0; i < 16; i++){
    const int dd = (tid >> 6) * 16 + i;
    const int nn2 = tid & 63;
    vT[(size_t)bh * 64 * NP + (size_t)dd * NP + n0 + nn2] = vt[nn2][dd];
  }
}

// ---------- pack mask bytes into bits: mbits[b][row<NP][MW] ----------
__launch_bounds__(256)
__global__ void mask_pack(const u8* __restrict__ mask, u32* __restrict__ mbits){
  const int idx = blockIdx.x * 256 + threadIdx.x;
  if (idx >= BB * NP * MW) return;
  const int word = idx % MW;
  const int row  = (idx / MW) % NP;
  const int b    = idx / (MW * NP);
  u32 bits = 0;
  if (row < NN){
    const u8* mrow = mask + (size_t)b * NN * NN + (size_t)row * NN;
    const int c0 = word * 32;
    const int lim = (NN - c0 < 32) ? (NN - c0) : 32;
    for (int j = 0; j < lim; j++) bits |= (u32)(mrow[c0 + j] != 0) << j;
  }
  mbits[idx] = bits;
}

// ---------- flash attention v9 (verbatim R11/R12): 2-phase K/V prefetch + setprio ----------
__launch_bounds__(512)
__global__ void attn_flash(const u16* __restrict__ q, const u16* __restrict__ k,
                           const u16* __restrict__ vT, const float* __restrict__ bias,
                           const u32* __restrict__ mbits,
                           float* __restrict__ S, u16* __restrict__ obuf){
  __shared__ u16 Ks[2][128 * 64];  // 2 x 16 KB, chunk ^= row&7 (source-side)
  __shared__ u16 Vs[2][64 * 128];  // 2 x 16 KB, chunk ^= row&15

  const int f = blockIdx.x;
  const int xcd = f & 7, ii = f >> 3;
  const int hl = ii / 72, rem = ii % 72;
  const int rt = rem >> 3, b = rem & 7;
  const int h = xcd * 2 + hl;
  const int bh = b * 16 + h;
  const int tid = threadIdx.x, w = tid >> 6, l = tid & 63;
  const int lg = l >> 4, lo = l & 15;
  const int row0 = rt * 128 + w * 16;
  const u16* qb = q + (size_t)bh * NP * 64;
  const u16* kb = k + (size_t)bh * NP * 64;
  const u16* vb = vT + (size_t)bh * 64 * NP;
  const float* bias_h = bias + (size_t)h * NN * NN;
  const u32* mrow_b = mbits + (size_t)b * NP * MW;
  float* Sb = S + (size_t)bh * NN * NN;

  s16x8 qf[2];
#pragma unroll
  for (int kk = 0; kk < 2; kk++)
    qf[kk] = *(const s16x8*)(qb + (size_t)(row0 + lo) * 64 + kk * 32 + lg * 8);

  float m_run = -1e30f, l_run = 0.f;
  f32x4 acc_o[4] = {};

  auto stage = [&](int buf, int ct){
    const int cb = ct * 128;
#pragma unroll
    for (int i = 0; i < 2; i++){
      const int chunk = tid + i * 512;
      const int row = chunk >> 3, cs = chunk & 7;
      const int cg = cs ^ (row & 7);
      gload16(kb + (size_t)(cb + row) * 64 + cg * 8, Ks[buf] + (size_t)chunk * 8);
    }
#pragma unroll
    for (int i = 0; i < 2; i++){
      const int chunk = tid + i * 512;
      const int row = chunk >> 4, cs = chunk & 15;
      const int cg = cs ^ (row & 15);
      gload16(vb + (size_t)row * NP + cb + cg * 8, Vs[buf] + (size_t)chunk * 8);
    }
  };

  stage(0, 0);                           // prologue: tile 0 in flight

  for (int ct = 0; ct < 9; ct++){
    const int cb = ct * 128;
    const int cur = ct & 1;
    if (ct < 8){
      stage(cur ^ 1, ct + 1);            // issue next tile (flies during compute)
      asm volatile("s_waitcnt vmcnt(4)" ::: "memory");  // cur tile landed; next in flight
    } else {
      asm volatile("s_waitcnt vmcnt(0)" ::: "memory");  // tail: drain all
    }
    __builtin_amdgcn_s_barrier();        // all waves' cur-tile data visible
    __builtin_amdgcn_sched_barrier(0);
    const u16* KsC = Ks[cur];
    const u16* VsC = Vs[cur];

    f32x4 sa[8] = {};
    // S^T = K_perm x Q
    __builtin_amdgcn_s_setprio(1);
#pragma unroll
    for (int m2 = 0; m2 < 8; m2++){
      const int rl = (m2 >> 1) * 32 + (lo >> 2) * 8 + (m2 & 1) * 4 + (lo & 3);
      const s16x8 kf0 = *(const s16x8*)(KsC + rl * 64 + ((lg ^ (rl & 7)) << 3));
      const s16x8 kf1 = *(const s16x8*)(KsC + rl * 64 + (((4 + lg) ^ (rl & 7)) << 3));
      sa[m2] = __builtin_amdgcn_mfma_f32_16x16x32_bf16(kf0, qf[0], sa[m2], 0, 0, 0);
      sa[m2] = __builtin_amdgcn_mfma_f32_16x16x32_bf16(kf1, qf[1], sa[m2], 0, 0, 0);
    }
    __builtin_amdgcn_s_setprio(0);
    // mask -> NEGV, + bias, write S; invalid k-cols -> -1e30
    {
      const int qr = row0 + lo;
      if (qr < NN){
        const u32* mrp = mrow_b + (size_t)qr * MW + ct * 4;
        u32 mb[4];
#pragma unroll
        for (int i = 0; i < 4; i++) mb[i] = mrp[i];
        const float* brow = bias_h + (size_t)qr * NN;
        float* srow = Sb + (size_t)qr * NN;
#pragma unroll
        for (int m2 = 0; m2 < 8; m2++){
          const int kc0 = cb + (m2 >> 1) * 32 + lg * 8 + (m2 & 1) * 4;
          const u32 bits = mb[m2 >> 1] >> (lg * 8 + (m2 & 1) * 4);
          f32x4 a = sa[m2];
          if (kc0 + 3 < NN){
            f32x4u bv = *(const f32x4u*)(brow + kc0);
#pragma unroll
            for (int jj = 0; jj < 4; jj++){
              float v = ((bits >> jj) & 1u) ? NEGV : a[jj];
              a[jj] = v + bv[jj];
            }
            *(f32x4u*)(srow + kc0) = a;
          } else {
#pragma unroll
            for (int jj = 0; jj < 4; jj++){
              if (kc0 + jj < NN){
                float v = ((bits >> jj) & 1u) ? NEGV : a[jj];
                v += brow[kc0 + jj];
                srow[kc0 + jj] = v;
                a[jj] = v;
              } else a[jj] = -1e30f;
            }
          }
          sa[m2] = a;
        }
      } else {
        const f32x4 z = {0.f, 0.f, 0.f, 0.f};
#pragma unroll
        for (int m2 = 0; m2 < 8; m2++) sa[m2] = z;
      }
    }
    // online softmax
    float sc;
    {
      float mt = -1e30f;
#pragma unroll
      for (int m2 = 0; m2 < 8; m2++){
        f32x4 a = sa[m2];
        mt = fmaxf(mt, fmaxf(fmaxf(a[0], a[1]), fmaxf(a[2], a[3])));
      }
      mt = fmaxf(mt, __shfl_xor(mt, 16, 64));
      mt = fmaxf(mt, __shfl_xor(mt, 32, 64));
      const float mn = fmaxf(m_run, mt);
      sc = __expf(m_run - mn);
      float p = 0.f;
#pragma unroll
      for (int m2 = 0; m2 < 8; m2++){
        f32x4 a = sa[m2];
        const float e0 = __expf(a[0] - mn), e1 = __expf(a[1] - mn);
        const float e2 = __expf(a[2] - mn), e3 = __expf(a[3] - mn);
        p += (e0 + e1) + (e2 + e3);
        sa[m2][0] = __uint_as_float(cvt_pk_bf16(e0, e1));
        sa[m2][1] = __uint_as_float(cvt_pk_bf16(e2, e3));
      }
      p += __shfl_xor(p, 16, 64);
      p += __shfl_xor(p, 32, 64);
      l_run = l_run * sc + p;
      m_run = mn;
    }
    // rescale O
#pragma unroll
    for (int jj = 0; jj < 4; jj++){
      const float s = __shfl(sc, (l & 48) + lg * 4 + jj, 64);
#pragma unroll
      for (int nd = 0; nd < 4; nd++) acc_o[nd][jj] *= s;
    }
    // PV
    __builtin_amdgcn_s_setprio(1);
#pragma unroll
    for (int kc = 0; kc < 4; kc++){
      union { u32 d[4]; s16x8 v8; } af;
      af.d[0] = __float_as_uint(sa[2 * kc][0]);
      af.d[1] = __float_as_uint(sa[2 * kc][1]);
      af.d[2] = __float_as_uint(sa[2 * kc + 1][0]);
      af.d[3] = __float_as_uint(sa[2 * kc + 1][1]);
#pragma unroll
      for (int nd = 0; nd < 4; nd++){
        const int vrow = nd * 16 + lo;
        const s16x8 vf = *(const s16x8*)(VsC + vrow * 128 + (((kc * 4 + lg) ^ (vrow & 15)) << 3));
        acc_o[nd] = __builtin_amdgcn_mfma_f32_16x16x32_bf16(af.v8, vf, acc_o[nd], 0, 0, 0);
      }
    }
    __builtin_amdgcn_s_setprio(0);
    __builtin_amdgcn_s_barrier();        // all waves done reading cur buffer
    __builtin_amdgcn_sched_barrier(0);
  }
  // epilogue: O * 1/l
  {
    const float li = 1.f / l_run;
#pragma unroll
    for (int jj = 0; jj < 4; jj++){
      const float il = __shfl(li, (l & 48) + lg * 4 + jj, 64);
      const int qr = row0 + lg * 4 + jj;
      if (qr < NN){
        const size_t base = ((size_t)b * NN + qr) * CC + (size_t)h * 64;
#pragma unroll
        for (int nd = 0; nd < 4; nd++)
          obuf[base + nd * 16 + lo] = f2bf(acc_o[nd][jj] * il);
      }
    }
  }
}

// ---------- zero pad rows of obuf (tokens TOK..MP) ----------
__launch_bounds__(256)
__global__ void zero_pad_rows(u16* __restrict__ buf){
  const size_t i = (size_t)blockIdx.x * 256 + threadIdx.x;
  buf[(size_t)TOK * CC + i] = 0;
}

extern "C" void kernel_launch(void* const* d_in, const int* in_sizes, int n_in,
                              void* d_out, int out_size, void* d_ws, size_t ws_size,
                              hipStream_t stream){
  const float* x     = (const float*)d_in[0];
  const float* rpb   = (const float*)d_in[1];
  const u8*    mask  = (const u8*)d_in[2];
  const float* ln1g  = (const float*)d_in[3];
  const float* ln1b  = (const float*)d_in[4];
  const float* qkvw  = (const float*)d_in[5];
  const float* qkvb  = (const float*)d_in[6];
  const float* projw = (const float*)d_in[7];
  const float* projb = (const float*)d_in[8];
  const float* ln2g  = (const float*)d_in[9];
  const float* ln2b  = (const float*)d_in[10];
  const float* fc1w  = (const float*)d_in[11];
  const float* fc1b  = (const float*)d_in[12];
  const float* fc2w  = (const float*)d_in[13];
  const float* fc2b  = (const float*)d_in[14];

  float* out_x = (float*)d_out;
  float* out_S = out_x + (size_t)BB * NN * CC;

  char* wsb = (char*)d_ws;
  size_t off = 0;
  auto alloc = [&](size_t bytes) -> char* {
    char* p = wsb + off; off += (bytes + 255) & ~(size_t)255; return p;
  };
  u16* h1     = (u16*)alloc((size_t)MP * CC * 2);
  u16* qkvbuf = (u16*)alloc((size_t)MP * 3072 * 2);
  u16* h3     = h1;                                    // [MP][4096] aliases h1+qkvbuf
  u16* qkvwt  = (u16*)alloc((size_t)3072 * 1024 * 2);
  u16* projwt = (u16*)alloc((size_t)1024 * 1024 * 2);
  u16* fc1wt  = (u16*)alloc((size_t)4096 * 1024 * 2);
  u16* fc2wt  = (u16*)alloc((size_t)1024 * 4096 * 2);
  u16* qq     = (u16*)alloc((size_t)128 * NP * 64 * 2);
  u16* kk     = (u16*)alloc((size_t)128 * NP * 64 * 2);
  u16* vT     = (u16*)alloc((size_t)128 * 64 * NP * 2);
  u32* mbits  = (u32*)alloc((size_t)BB * NP * MW * 4);
  u16* obuf   = (u16*)alloc((size_t)MP * CC * 2);
  float* x1   = (float*)alloc((size_t)MP * CC * 4);
  u16* h2in   = (u16*)alloc((size_t)MP * CC * 2);

  cvt_transpose<<<dim3(3072/32, 1024/32), 256, 0, stream>>>(qkvw, qkvwt, 1024, 3072);
  cvt_transpose<<<dim3(1024/32, 1024/32), 256, 0, stream>>>(projw, projwt, 1024, 1024);
  cvt_transpose<<<dim3(4096/32, 1024/32), 256, 0, stream>>>(fc1w, fc1wt, 1024, 4096);
  cvt_transpose<<<dim3(1024/32, 4096/32), 256, 0, stream>>>(fc2w, fc2wt, 4096, 1024);
  ln_kernel<<<MP, 256, 0, stream>>>(x, ln1g, ln1b, h1, TOK);
  gemm_nt<0><<<dim3(3072/128, MP/128), 256, 0, stream>>>(h1, qkvwt, qkvb, 1024, 3072, nullptr, nullptr, qkvbuf);
  reorder_qkv<<<dim3(NP/64, 128), 256, 0, stream>>>(qkvbuf, qq, kk, vT);
  mask_pack<<<(BB * NP * MW + 255) / 256, 256, 0, stream>>>(mask, mbits);
  zero_pad_rows<<<(MP - TOK) * CC / 256, 256, 0, stream>>>(obuf);
  attn_flash<<<dim3(1152), 512, 0, stream>>>(qq, kk, vT, rpb, mbits, out_S, obuf);
  gemm_nt<1><<<dim3(1024/128, MP/128), 256, 0, stream>>>(obuf, projwt, projb, 1024, 1024, x, x1, nullptr);
  ln_kernel<<<MP, 256, 0, stream>>>(x1, ln2g, ln2b, h2in, TOK);
  gemm_nt<2><<<dim3(4096/128, MP/128), 256, 0, stream>>>(h2in, fc1wt, fc1b, 1024, 4096, nullptr, nullptr, h3);
  gemm_nt<3><<<dim3(1024/128, MP/128), 256, 0, stream>>>(h3, fc2wt, fc2b, 4096, 1024, x1, out_x, nullptr);
}